// Round 7
// baseline (745.724 us; speedup 1.0000x reference)
//
#include <hip/hip_runtime.h>

#define DD 64
#define TPAD 66
#define RB 256         // rows per bucket
#define RB_SHIFT 8
#define CAP 4608       // LDS-sorted edge capacity per bucket (avg 4096, +8 sigma)
#define NBLKA 512      // blocks in the two bucketing passes (pow2; must match)
#define NBLKA_SHIFT 9
#define BMAX 1024      // max buckets (n <= BMAX*RB, col fits 18 bits)
#define COLM 0x3FFFF
#define OVFCAP 65536   // overflow edge list capacity (correctness-only path)

static __device__ __forceinline__ float leaky(float x) {
    return x > 0.f ? x : 0.2f * x;
}

__global__ void concat_kernel(const float4* __restrict__ ue, const float4* __restrict__ ie,
                              float4* __restrict__ ego, int n_user4, int total4) {
    int idx = blockIdx.x * blockDim.x + threadIdx.x;
    if (idx >= total4) return;
    ego[idx] = (idx < n_user4) ? ue[idx] : ie[idx - n_user4];
}

// pass A: per-(bucket, block) histogram via LDS — no global atomics.
// counts stored block-major (transposed) so the writes per block coalesce.
__global__ void bhist_kernel(const int* __restrict__ rows, int* __restrict__ counts_t, int nnz,
                             int nbuckets) {
    __shared__ int h[BMAX];
    int tid = threadIdx.x, blk = blockIdx.x;
    for (int i = tid; i < nbuckets; i += 256) h[i] = 0;
    __syncthreads();
    int chunk = (nnz + NBLKA - 1) / NBLKA;
    int lo = blk * chunk, hi = min(nnz, lo + chunk);
    for (int e = lo + tid; e < hi; e += 256) atomicAdd(&h[rows[e] >> RB_SHIFT], 1);
    __syncthreads();
    for (int i = tid; i < nbuckets; i += 256) counts_t[blk * nbuckets + i] = h[i];
}

// scan over flat order f = bucket*NBLKA + blk, reading transposed counts.
__global__ void scan1_kernel(const int* __restrict__ counts_t, int* __restrict__ offsets,
                             int* __restrict__ blocksums, int flat, int nbuckets) {
    __shared__ int tmp[1024];
    int t = threadIdx.x;
    int g = blockIdx.x * 1024 + t;
    int x = 0;
    if (g < flat) {
        int i = g >> NBLKA_SHIFT, blk = g & (NBLKA - 1);
        x = counts_t[blk * nbuckets + i];
    }
    tmp[t] = x;
    __syncthreads();
    for (int off = 1; off < 1024; off <<= 1) {
        int y = (t >= off) ? tmp[t - off] : 0;
        __syncthreads();
        tmp[t] += y;
        __syncthreads();
    }
    if (g < flat) offsets[g + 1] = tmp[t];
    if (t == 1023) blocksums[blockIdx.x] = tmp[t];
    if (g == 0) offsets[0] = 0;
}

__global__ void scan2_kernel(int* blocksums, int nb) {
    __shared__ int tmp[1024];
    int t = threadIdx.x;
    int v = (t < nb) ? blocksums[t] : 0;
    tmp[t] = v;
    __syncthreads();
    for (int off = 1; off < 1024; off <<= 1) {
        int y = (t >= off) ? tmp[t - off] : 0;
        __syncthreads();
        tmp[t] += y;
        __syncthreads();
    }
    if (t < nb) blocksums[t] = tmp[t] - v;  // exclusive base per block
}

__global__ void scan3_kernel(int* __restrict__ offsets, const int* __restrict__ blocksums,
                             int n) {
    int g = blockIdx.x * 1024 + threadIdx.x;
    if (g < n) offsets[g + 1] += blocksums[blockIdx.x];
}

// pass B: write each edge into its block-private contiguous slot range per bucket.
__global__ void bscatter_kernel(const int* __restrict__ rows, const int* __restrict__ cols,
                                const float* __restrict__ vals, const int* __restrict__ offsets,
                                int2* __restrict__ csr_cv, int nnz, int nbuckets) {
    __shared__ int cur[BMAX];
    int tid = threadIdx.x, blk = blockIdx.x;
    for (int i = tid; i < nbuckets; i += 256) cur[i] = offsets[i * NBLKA + blk];
    __syncthreads();
    int chunk = (nnz + NBLKA - 1) / NBLKA;
    int lo = blk * chunk, hi = min(nnz, lo + chunk);
    for (int e = lo + tid; e < hi; e += 256) {
        int r = rows[e];
        int p = atomicAdd(&cur[r >> RB_SHIFT], 1);
        int2 cv;
        cv.x = ((r & (RB - 1)) << 18) | cols[e];  // row_low(8b) | col(18b)
        cv.y = __float_as_int(vals[e]);
        csr_cv[p] = cv;
    }
}

// ONE-TIME sort: per bucket, counting-sort edges by row in LDS, write back to
// global (coalesced) and emit full per-row CSR rowoff. Buckets are contiguous
// in row space so concatenated sorted buckets = globally row-sorted CSR.
// (R6 redid this sort inside spmm every layer — 3x wasted, and the 40KB LDS
// capped spmm occupancy at 23%.)
__global__ void __launch_bounds__(256) sort_kernel(
    const int* __restrict__ offsets, const int2* __restrict__ csr_cv,
    int2* __restrict__ sorted_cv, int* __restrict__ rowoff_g,
    int4* __restrict__ ovf, int* __restrict__ ovf_cnt, int nnz, int nbuckets) {
    __shared__ int2 sorted[CAP];
    __shared__ int hist[RB];
    __shared__ int rowoff[RB + 1];
    __shared__ int cur[RB];
    int tid = threadIdx.x;
    int b = blockIdx.x;
    int s = offsets[b * NBLKA];
    int e = offsets[(b + 1) * NBLKA];
    int m = min(e - s, CAP);

    hist[tid] = 0;
    __syncthreads();
    for (int k = s + tid; k < s + m; k += 256)
        atomicAdd(&hist[((unsigned)csr_cv[k].x) >> 18], 1);
    __syncthreads();
    for (int off = 1; off < RB; off <<= 1) {
        int v = (tid >= off) ? hist[tid - off] : 0;
        __syncthreads();
        hist[tid] += v;
        __syncthreads();
    }
    rowoff[tid + 1] = hist[tid];
    if (tid == 0) rowoff[0] = 0;
    __syncthreads();
    cur[tid] = rowoff[tid];
    __syncthreads();
    for (int k = s + tid; k < s + m; k += 256) {
        int2 cv = csr_cv[k];
        int p = atomicAdd(&cur[((unsigned)cv.x) >> 18], 1);
        sorted[p] = cv;
    }
    __syncthreads();
    // coalesced writeback + per-row global offsets
    for (int k = tid; k < m; k += 256) sorted_cv[s + k] = sorted[k];
    rowoff_g[b * RB + tid] = s + rowoff[tid];
    if (b == 0 && tid == 0) rowoff_g[nbuckets * RB] = nnz;
    // overflow (statistically never: CAP = avg + 8 sigma) -> global list
    for (int k = s + CAP + tid; k < e; k += 256) {
        int2 cv = csr_cv[k];
        int p = atomicAdd(ovf_cnt, 1);
        if (p < OVFCAP) {
            int4 o;
            o.x = b * RB + (int)(((unsigned)cv.x) >> 18);
            o.y = cv.x & COLM;
            o.z = cv.y;
            o.w = 0;
            ovf[p] = o;
        }
    }
}

// SpMM over the pre-sorted CSR: 4 rows per wave, 16 lanes per row, float4 per
// lane, 4 gathers in flight. No LDS -> full occupancy (R6: 23%, latency-bound).
__global__ void spmm_csr_kernel(const float4* __restrict__ ego4,
                                const int* __restrict__ rowoff,
                                const int2* __restrict__ sorted_cv,
                                float4* __restrict__ side4, int n) {
    int wid = (blockIdx.x * blockDim.x + threadIdx.x) >> 6;
    int lane = threadIdx.x & 63;
    int sub = lane >> 4, l16 = lane & 15;
    int row = wid * 4 + sub;
    if (row >= n) return;
    int s = rowoff[row], e = rowoff[row + 1];
    float4 acc = {0.f, 0.f, 0.f, 0.f};
    int k = s;
    for (; k + 4 <= e; k += 4) {
        int2 c0 = sorted_cv[k];
        int2 c1 = sorted_cv[k + 1];
        int2 c2 = sorted_cv[k + 2];
        int2 c3 = sorted_cv[k + 3];
        float4 g0 = ego4[(c0.x & COLM) * 16 + l16];
        float4 g1 = ego4[(c1.x & COLM) * 16 + l16];
        float4 g2 = ego4[(c2.x & COLM) * 16 + l16];
        float4 g3 = ego4[(c3.x & COLM) * 16 + l16];
        float v0 = __int_as_float(c0.y), v1 = __int_as_float(c1.y);
        float v2 = __int_as_float(c2.y), v3 = __int_as_float(c3.y);
        acc.x += v0 * g0.x; acc.y += v0 * g0.y; acc.z += v0 * g0.z; acc.w += v0 * g0.w;
        acc.x += v1 * g1.x; acc.y += v1 * g1.y; acc.z += v1 * g1.z; acc.w += v1 * g1.w;
        acc.x += v2 * g2.x; acc.y += v2 * g2.y; acc.z += v2 * g2.z; acc.w += v2 * g2.w;
        acc.x += v3 * g3.x; acc.y += v3 * g3.y; acc.z += v3 * g3.z; acc.w += v3 * g3.w;
    }
    for (; k < e; ++k) {
        int2 cv = sorted_cv[k];
        float4 g = ego4[(cv.x & COLM) * 16 + l16];
        float v = __int_as_float(cv.y);
        acc.x += v * g.x; acc.y += v * g.y; acc.z += v * g.z; acc.w += v * g.w;
    }
    side4[row * 16 + l16] = acc;
}

// correctness-only fixup for sort overflow edges (normally ovf_cnt == 0)
__global__ void ovf_fix_kernel(const int4* __restrict__ ovf, const int* __restrict__ ovf_cnt,
                               const float* __restrict__ ego, float* __restrict__ side) {
    int total = min(*ovf_cnt, OVFCAP);
    for (int i = blockIdx.x * blockDim.x + threadIdx.x; i < total * DD;
         i += gridDim.x * blockDim.x) {
        int e = i >> 6, d = i & 63;
        int4 o = ovf[e];
        atomicAdd(&side[o.x * DD + d], __int_as_float(o.z) * ego[o.y * DD + d]);
    }
}

// ego_new = leaky(side@Wgc + bgc) + leaky((ego*side)@Wbi + bbi), in-place on ego.
// unroll 4 + launch_bounds(256,4): full unroll blew VGPRs to 256 + spills (R2).
__global__ void __launch_bounds__(256, 4) transform_kernel(
    const float* __restrict__ side, float* __restrict__ ego,
    const float* __restrict__ Wgc, const float* __restrict__ bgc,
    const float* __restrict__ Wbi, const float* __restrict__ bbi, int n) {
    __shared__ __align__(16) float sWg[DD * DD];
    __shared__ __align__(16) float sWb[DD * DD];
    __shared__ __align__(16) float sS[DD * TPAD];
    __shared__ __align__(16) float sP[DD * TPAD];
    int tid = threadIdx.x;
    int base = blockIdx.x * 32;

    for (int idx = tid * 4; idx < DD * DD; idx += 1024) {
        *(float4*)&sWg[idx] = *(const float4*)&Wgc[idx];
        *(float4*)&sWb[idx] = *(const float4*)&Wbi[idx];
    }
    for (int idx = tid; idx < 32 * DD; idx += 256) {
        int nl = idx >> 6, k = idx & 63;
        int node = base + nl;
        float sv = 0.f, ev = 0.f;
        if (node < n) {
            sv = side[node * DD + k];
            ev = ego[node * DD + k];
        }
        sS[k * TPAD + nl] = sv;
        sP[k * TPAD + nl] = ev * sv;
    }
    __syncthreads();

    int col4 = (tid & 15) * 4;
    int n2 = (tid >> 4) * 2;
    float acc1[2][4] = {{0.f, 0.f, 0.f, 0.f}, {0.f, 0.f, 0.f, 0.f}};
    float acc2[2][4] = {{0.f, 0.f, 0.f, 0.f}, {0.f, 0.f, 0.f, 0.f}};

#pragma unroll 4
    for (int k = 0; k < DD; ++k) {
        float2 sv = *(const float2*)&sS[k * TPAD + n2];
        float2 pv = *(const float2*)&sP[k * TPAD + n2];
        float4 wg = *(const float4*)&sWg[k * DD + col4];
        float4 wb = *(const float4*)&sWb[k * DD + col4];
        acc1[0][0] += sv.x * wg.x; acc1[0][1] += sv.x * wg.y;
        acc1[0][2] += sv.x * wg.z; acc1[0][3] += sv.x * wg.w;
        acc1[1][0] += sv.y * wg.x; acc1[1][1] += sv.y * wg.y;
        acc1[1][2] += sv.y * wg.z; acc1[1][3] += sv.y * wg.w;
        acc2[0][0] += pv.x * wb.x; acc2[0][1] += pv.x * wb.y;
        acc2[0][2] += pv.x * wb.z; acc2[0][3] += pv.x * wb.w;
        acc2[1][0] += pv.y * wb.x; acc2[1][1] += pv.y * wb.y;
        acc2[1][2] += pv.y * wb.z; acc2[1][3] += pv.y * wb.w;
    }

    float4 bg = *(const float4*)&bgc[col4];
    float4 bb = *(const float4*)&bbi[col4];
#pragma unroll
    for (int a = 0; a < 2; ++a) {
        int node = base + n2 + a;
        if (node < n) {
            float4 o;
            o.x = leaky(acc1[a][0] + bg.x) + leaky(acc2[a][0] + bb.x);
            o.y = leaky(acc1[a][1] + bg.y) + leaky(acc2[a][1] + bb.y);
            o.z = leaky(acc1[a][2] + bg.z) + leaky(acc2[a][2] + bb.z);
            o.w = leaky(acc1[a][3] + bg.w) + leaky(acc2[a][3] + bb.w);
            *(float4*)&ego[node * DD + col4] = o;
        }
    }
}

__global__ void gather_kernel(const float* __restrict__ ego, const int* __restrict__ u,
                              const int* __restrict__ ii, const int* __restrict__ jj,
                              float* __restrict__ out, int layer, int B, int n_users,
                              int normalize) {
    int wid = (blockIdx.x * blockDim.x + threadIdx.x) >> 6;
    int lane = threadIdx.x & 63;
    if (wid >= 3 * B) return;
    int arr = wid / B;
    int b = wid - arr * B;
    int node = (arr == 0) ? u[b] : ((arr == 1) ? n_users + ii[b] : n_users + jj[b]);
    float v = ego[node * DD + lane];
    if (normalize) {
        float ss = v * v;
#pragma unroll
        for (int m = 32; m; m >>= 1) ss += __shfl_xor(ss, m, 64);
        v /= fmaxf(sqrtf(ss), 1e-12f);
    }
    out[wid * 256 + layer * DD + lane] = v;
}

extern "C" void kernel_launch(void* const* d_in, const int* in_sizes, int n_in,
                              void* d_out, int out_size, void* d_ws, size_t ws_size,
                              hipStream_t stream) {
    const float* user_emb = (const float*)d_in[0];
    const float* item_emb = (const float*)d_in[1];
    const float* W_gc = (const float*)d_in[2];
    const float* b_gc = (const float*)d_in[3];
    const float* W_bi = (const float*)d_in[4];
    const float* b_bi = (const float*)d_in[5];
    const float* adj_vals = (const float*)d_in[6];
    const int* adj_rows = (const int*)d_in[7];
    const int* adj_cols = (const int*)d_in[8];
    const int* u = (const int*)d_in[9];
    const int* ii = (const int*)d_in[10];
    const int* jj = (const int*)d_in[11];
    float* out = (float*)d_out;

    const int D = DD;
    int n_users = in_sizes[0] / D;
    int n_items = in_sizes[1] / D;
    int n = n_users + n_items;
    int nnz = in_sizes[6];
    int B = in_sizes[9];
    int L = in_sizes[2] / (D * D);

    int nbuckets = (n + RB - 1) / RB;      // 586
    int flat = nbuckets * NBLKA;

    char* ws = (char*)d_ws;
    auto alloc = [&](size_t bytes) {
        char* p = ws;
        ws += (bytes + 255) & ~(size_t)255;
        return p;
    };
    float* ego = (float*)alloc((size_t)n * D * 4);
    float* side = (float*)alloc((size_t)n * D * 4);
    int* counts_t = (int*)alloc((size_t)flat * 4);
    int* offsets = (int*)alloc((size_t)(flat + 1) * 4);
    int* blocksums = (int*)alloc(4096);
    int2* csr_cv = (int2*)alloc((size_t)nnz * 8);
    int2* sorted_cv = (int2*)alloc((size_t)nnz * 8);
    int* rowoff = (int*)alloc((size_t)(nbuckets * RB + 1) * 4);
    int4* ovf = (int4*)alloc((size_t)OVFCAP * 16);
    int* ovf_cnt = (int*)alloc(256);

    // 1. ego = concat(user_emb, item_emb)
    int total4 = n * D / 4, nu4 = n_users * D / 4;
    concat_kernel<<<(total4 + 255) / 256, 256, 0, stream>>>(
        (const float4*)user_emb, (const float4*)item_emb, (float4*)ego, nu4, total4);

    // 2. layer-0 slice of the output (raw ego, no normalization)
    int grows = 3 * B;
    gather_kernel<<<(grows + 3) / 4, 256, 0, stream>>>(ego, u, ii, jj, out, 0, B, n_users, 0);

    // 3. bucketed CSR build + ONE row-sort (graph identical across layers)
    hipMemsetAsync(ovf_cnt, 0, 4, stream);
    bhist_kernel<<<NBLKA, 256, 0, stream>>>(adj_rows, counts_t, nnz, nbuckets);
    int nblk1 = (flat + 1023) / 1024;
    scan1_kernel<<<nblk1, 1024, 0, stream>>>(counts_t, offsets, blocksums, flat, nbuckets);
    scan2_kernel<<<1, 1024, 0, stream>>>(blocksums, nblk1);
    scan3_kernel<<<nblk1, 1024, 0, stream>>>(offsets, blocksums, flat);
    bscatter_kernel<<<NBLKA, 256, 0, stream>>>(adj_rows, adj_cols, adj_vals, offsets, csr_cv,
                                               nnz, nbuckets);
    sort_kernel<<<nbuckets, 256, 0, stream>>>(offsets, csr_cv, sorted_cv, rowoff, ovf, ovf_cnt,
                                              nnz, nbuckets);

    // 4. layers
    int spmm_waves = (n + 3) / 4;
    int spmm_blocks = (spmm_waves * 64 + 255) / 256;
    for (int l = 0; l < L; ++l) {
        spmm_csr_kernel<<<spmm_blocks, 256, 0, stream>>>(
            (const float4*)ego, rowoff, sorted_cv, (float4*)side, n);
        ovf_fix_kernel<<<64, 256, 0, stream>>>(ovf, ovf_cnt, ego, side);
        transform_kernel<<<(n + 31) / 32, 256, 0, stream>>>(
            side, ego, W_gc + (size_t)l * D * D, b_gc + (size_t)l * D,
            W_bi + (size_t)l * D * D, b_bi + (size_t)l * D, n);
        gather_kernel<<<(grows + 3) / 4, 256, 0, stream>>>(ego, u, ii, jj, out, l + 1, B,
                                                           n_users, 1);
    }
}

// Round 8
// 637.292 us; speedup vs baseline: 1.1701x; 1.1701x over previous
//
#include <hip/hip_runtime.h>

#define DD 64
#define TPAD 66
#define RB 256         // rows per bucket
#define RB_SHIFT 8
#define CAP 4608       // LDS-sorted edge capacity per bucket (avg 4096, +8 sigma)
#define NBLKA 512      // blocks in the two bucketing passes (pow2; must match)
#define NBLKA_SHIFT 9
#define BMAX 1024      // max buckets (n <= BMAX*RB, col fits 18 bits)
#define COLM 0x3FFFF
#define OVFCAP 65536   // overflow edge list capacity (correctness-only path)

static __device__ __forceinline__ float leaky(float x) {
    return x > 0.f ? x : 0.2f * x;
}

// fp32 -> bf16 bits, round-to-nearest-even
static __device__ __forceinline__ unsigned short f2bf(float f) {
    unsigned u = __float_as_uint(f);
    unsigned r = 0x7FFFu + ((u >> 16) & 1u);
    return (unsigned short)((u + r) >> 16);
}
#define BF_LO(w) __int_as_float((int)((w) << 16))
#define BF_HI(w) __int_as_float((int)((w) & 0xFFFF0000u))

__global__ void concat_kernel(const float4* __restrict__ ue, const float4* __restrict__ ie,
                              float4* __restrict__ ego, ushort4* __restrict__ egob,
                              int n_user4, int total4) {
    int idx = blockIdx.x * blockDim.x + threadIdx.x;
    if (idx >= total4) return;
    float4 v = (idx < n_user4) ? ue[idx] : ie[idx - n_user4];
    ego[idx] = v;
    ushort4 b;
    b.x = f2bf(v.x); b.y = f2bf(v.y); b.z = f2bf(v.z); b.w = f2bf(v.w);
    egob[idx] = b;
}

// pass A: per-(bucket, block) histogram via LDS — no global atomics.
__global__ void bhist_kernel(const int* __restrict__ rows, int* __restrict__ counts_t, int nnz,
                             int nbuckets) {
    __shared__ int h[BMAX];
    int tid = threadIdx.x, blk = blockIdx.x;
    for (int i = tid; i < nbuckets; i += 256) h[i] = 0;
    __syncthreads();
    int chunk = (nnz + NBLKA - 1) / NBLKA;
    int lo = blk * chunk, hi = min(nnz, lo + chunk);
    for (int e = lo + tid; e < hi; e += 256) atomicAdd(&h[rows[e] >> RB_SHIFT], 1);
    __syncthreads();
    for (int i = tid; i < nbuckets; i += 256) counts_t[blk * nbuckets + i] = h[i];
}

// scan over flat order f = bucket*NBLKA + blk, reading transposed counts.
__global__ void scan1_kernel(const int* __restrict__ counts_t, int* __restrict__ offsets,
                             int* __restrict__ blocksums, int flat, int nbuckets) {
    __shared__ int tmp[1024];
    int t = threadIdx.x;
    int g = blockIdx.x * 1024 + t;
    int x = 0;
    if (g < flat) {
        int i = g >> NBLKA_SHIFT, blk = g & (NBLKA - 1);
        x = counts_t[blk * nbuckets + i];
    }
    tmp[t] = x;
    __syncthreads();
    for (int off = 1; off < 1024; off <<= 1) {
        int y = (t >= off) ? tmp[t - off] : 0;
        __syncthreads();
        tmp[t] += y;
        __syncthreads();
    }
    if (g < flat) offsets[g + 1] = tmp[t];
    if (t == 1023) blocksums[blockIdx.x] = tmp[t];
    if (g == 0) offsets[0] = 0;
}

__global__ void scan2_kernel(int* blocksums, int nb) {
    __shared__ int tmp[1024];
    int t = threadIdx.x;
    int v = (t < nb) ? blocksums[t] : 0;
    tmp[t] = v;
    __syncthreads();
    for (int off = 1; off < 1024; off <<= 1) {
        int y = (t >= off) ? tmp[t - off] : 0;
        __syncthreads();
        tmp[t] += y;
        __syncthreads();
    }
    if (t < nb) blocksums[t] = tmp[t] - v;  // exclusive base per block
}

__global__ void scan3_kernel(int* __restrict__ offsets, const int* __restrict__ blocksums,
                             int n) {
    int g = blockIdx.x * 1024 + threadIdx.x;
    if (g < n) offsets[g + 1] += blocksums[blockIdx.x];
}

// pass B: write each edge into its block-private contiguous slot range per bucket.
__global__ void bscatter_kernel(const int* __restrict__ rows, const int* __restrict__ cols,
                                const float* __restrict__ vals, const int* __restrict__ offsets,
                                int2* __restrict__ csr_cv, int nnz, int nbuckets) {
    __shared__ int cur[BMAX];
    int tid = threadIdx.x, blk = blockIdx.x;
    for (int i = tid; i < nbuckets; i += 256) cur[i] = offsets[i * NBLKA + blk];
    __syncthreads();
    int chunk = (nnz + NBLKA - 1) / NBLKA;
    int lo = blk * chunk, hi = min(nnz, lo + chunk);
    for (int e = lo + tid; e < hi; e += 256) {
        int r = rows[e];
        int p = atomicAdd(&cur[r >> RB_SHIFT], 1);
        int2 cv;
        cv.x = ((r & (RB - 1)) << 18) | cols[e];  // row_low(8b) | col(18b)
        cv.y = __float_as_int(vals[e]);
        csr_cv[p] = cv;
    }
}

// ONE-TIME sort: per bucket, counting-sort edges by row in LDS, write back to
// global (coalesced) and emit full per-row CSR rowoff.
__global__ void __launch_bounds__(256) sort_kernel(
    const int* __restrict__ offsets, const int2* __restrict__ csr_cv,
    int2* __restrict__ sorted_cv, int* __restrict__ rowoff_g,
    int4* __restrict__ ovf, int* __restrict__ ovf_cnt, int nnz, int nbuckets) {
    __shared__ int2 sorted[CAP];
    __shared__ int hist[RB];
    __shared__ int rowoff[RB + 1];
    __shared__ int cur[RB];
    int tid = threadIdx.x;
    int b = blockIdx.x;
    int s = offsets[b * NBLKA];
    int e = offsets[(b + 1) * NBLKA];
    int m = min(e - s, CAP);

    hist[tid] = 0;
    __syncthreads();
    for (int k = s + tid; k < s + m; k += 256)
        atomicAdd(&hist[((unsigned)csr_cv[k].x) >> 18], 1);
    __syncthreads();
    for (int off = 1; off < RB; off <<= 1) {
        int v = (tid >= off) ? hist[tid - off] : 0;
        __syncthreads();
        hist[tid] += v;
        __syncthreads();
    }
    rowoff[tid + 1] = hist[tid];
    if (tid == 0) rowoff[0] = 0;
    __syncthreads();
    cur[tid] = rowoff[tid];
    __syncthreads();
    for (int k = s + tid; k < s + m; k += 256) {
        int2 cv = csr_cv[k];
        int p = atomicAdd(&cur[((unsigned)cv.x) >> 18], 1);
        sorted[p] = cv;
    }
    __syncthreads();
    for (int k = tid; k < m; k += 256) sorted_cv[s + k] = sorted[k];
    rowoff_g[b * RB + tid] = s + rowoff[tid];
    if (b == 0 && tid == 0) rowoff_g[nbuckets * RB] = nnz;
    // overflow (statistically never: CAP = avg + 8 sigma) -> global list
    for (int k = s + CAP + tid; k < e; k += 256) {
        int2 cv = csr_cv[k];
        int p = atomicAdd(ovf_cnt, 1);
        if (p < OVFCAP) {
            int4 o;
            o.x = b * RB + (int)(((unsigned)cv.x) >> 18);
            o.y = cv.x & COLM;
            o.z = cv.y;
            o.w = 0;
            ovf[p] = o;
        }
    }
}

// SpMM over pre-sorted CSR, bf16 gather operand (fp32 vals + fp32 accumulate).
// 8 rows/wave, 8 lanes/row, uint4(= 8 bf16)/lane. Gather row = 128B instead of
// 256B: R7 showed 3.8 TB/s L2-fill ceiling on random 256B gathers (FETCH 289MB)
// — halving bytes + doubling L2 coverage is the only lever left.
__global__ void spmm_csr_kernel(const uint4* __restrict__ egob4,
                                const int* __restrict__ rowoff,
                                const int2* __restrict__ sorted_cv,
                                float4* __restrict__ side4, int n) {
    int wid = (blockIdx.x * blockDim.x + threadIdx.x) >> 6;
    int lane = threadIdx.x & 63;
    int sub = lane >> 3, l8 = lane & 7;
    int row = wid * 8 + sub;
    if (row >= n) return;
    int s = rowoff[row], e = rowoff[row + 1];
    float acc[8] = {0.f, 0.f, 0.f, 0.f, 0.f, 0.f, 0.f, 0.f};
    int k = s;
    for (; k + 4 <= e; k += 4) {
        int2 c0 = sorted_cv[k];
        int2 c1 = sorted_cv[k + 1];
        int2 c2 = sorted_cv[k + 2];
        int2 c3 = sorted_cv[k + 3];
        uint4 g0 = egob4[(c0.x & COLM) * 8 + l8];
        uint4 g1 = egob4[(c1.x & COLM) * 8 + l8];
        uint4 g2 = egob4[(c2.x & COLM) * 8 + l8];
        uint4 g3 = egob4[(c3.x & COLM) * 8 + l8];
        float v0 = __int_as_float(c0.y), v1 = __int_as_float(c1.y);
        float v2 = __int_as_float(c2.y), v3 = __int_as_float(c3.y);
        acc[0] += v0 * BF_LO(g0.x); acc[1] += v0 * BF_HI(g0.x);
        acc[2] += v0 * BF_LO(g0.y); acc[3] += v0 * BF_HI(g0.y);
        acc[4] += v0 * BF_LO(g0.z); acc[5] += v0 * BF_HI(g0.z);
        acc[6] += v0 * BF_LO(g0.w); acc[7] += v0 * BF_HI(g0.w);
        acc[0] += v1 * BF_LO(g1.x); acc[1] += v1 * BF_HI(g1.x);
        acc[2] += v1 * BF_LO(g1.y); acc[3] += v1 * BF_HI(g1.y);
        acc[4] += v1 * BF_LO(g1.z); acc[5] += v1 * BF_HI(g1.z);
        acc[6] += v1 * BF_LO(g1.w); acc[7] += v1 * BF_HI(g1.w);
        acc[0] += v2 * BF_LO(g2.x); acc[1] += v2 * BF_HI(g2.x);
        acc[2] += v2 * BF_LO(g2.y); acc[3] += v2 * BF_HI(g2.y);
        acc[4] += v2 * BF_LO(g2.z); acc[5] += v2 * BF_HI(g2.z);
        acc[6] += v2 * BF_LO(g2.w); acc[7] += v2 * BF_HI(g2.w);
        acc[0] += v3 * BF_LO(g3.x); acc[1] += v3 * BF_HI(g3.x);
        acc[2] += v3 * BF_LO(g3.y); acc[3] += v3 * BF_HI(g3.y);
        acc[4] += v3 * BF_LO(g3.z); acc[5] += v3 * BF_HI(g3.z);
        acc[6] += v3 * BF_LO(g3.w); acc[7] += v3 * BF_HI(g3.w);
    }
    for (; k < e; ++k) {
        int2 cv = sorted_cv[k];
        uint4 g = egob4[(cv.x & COLM) * 8 + l8];
        float v = __int_as_float(cv.y);
        acc[0] += v * BF_LO(g.x); acc[1] += v * BF_HI(g.x);
        acc[2] += v * BF_LO(g.y); acc[3] += v * BF_HI(g.y);
        acc[4] += v * BF_LO(g.z); acc[5] += v * BF_HI(g.z);
        acc[6] += v * BF_LO(g.w); acc[7] += v * BF_HI(g.w);
    }
    float4 o0 = {acc[0], acc[1], acc[2], acc[3]};
    float4 o1 = {acc[4], acc[5], acc[6], acc[7]};
    side4[row * 16 + l8 * 2] = o0;
    side4[row * 16 + l8 * 2 + 1] = o1;
}

// correctness-only fixup for sort overflow edges (normally ovf_cnt == 0)
__global__ void ovf_fix_kernel(const int4* __restrict__ ovf, const int* __restrict__ ovf_cnt,
                               const float* __restrict__ ego, float* __restrict__ side) {
    int total = min(*ovf_cnt, OVFCAP);
    for (int i = blockIdx.x * blockDim.x + threadIdx.x; i < total * DD;
         i += gridDim.x * blockDim.x) {
        int e = i >> 6, d = i & 63;
        int4 o = ovf[e];
        atomicAdd(&side[o.x * DD + d], __int_as_float(o.z) * ego[o.y * DD + d]);
    }
}

// ego_new = leaky(side@Wgc + bgc) + leaky((ego*side)@Wbi + bbi), in-place on ego,
// plus bf16 mirror write for the next layer's spmm gathers.
// unroll 4 + launch_bounds(256,4): full unroll blew VGPRs to 256 + spills (R2).
__global__ void __launch_bounds__(256, 4) transform_kernel(
    const float* __restrict__ side, float* __restrict__ ego, ushort4* __restrict__ egob,
    const float* __restrict__ Wgc, const float* __restrict__ bgc,
    const float* __restrict__ Wbi, const float* __restrict__ bbi, int n) {
    __shared__ __align__(16) float sWg[DD * DD];
    __shared__ __align__(16) float sWb[DD * DD];
    __shared__ __align__(16) float sS[DD * TPAD];
    __shared__ __align__(16) float sP[DD * TPAD];
    int tid = threadIdx.x;
    int base = blockIdx.x * 32;

    for (int idx = tid * 4; idx < DD * DD; idx += 1024) {
        *(float4*)&sWg[idx] = *(const float4*)&Wgc[idx];
        *(float4*)&sWb[idx] = *(const float4*)&Wbi[idx];
    }
    for (int idx = tid; idx < 32 * DD; idx += 256) {
        int nl = idx >> 6, k = idx & 63;
        int node = base + nl;
        float sv = 0.f, ev = 0.f;
        if (node < n) {
            sv = side[node * DD + k];
            ev = ego[node * DD + k];
        }
        sS[k * TPAD + nl] = sv;
        sP[k * TPAD + nl] = ev * sv;
    }
    __syncthreads();

    int col4 = (tid & 15) * 4;
    int n2 = (tid >> 4) * 2;
    float acc1[2][4] = {{0.f, 0.f, 0.f, 0.f}, {0.f, 0.f, 0.f, 0.f}};
    float acc2[2][4] = {{0.f, 0.f, 0.f, 0.f}, {0.f, 0.f, 0.f, 0.f}};

#pragma unroll 4
    for (int k = 0; k < DD; ++k) {
        float2 sv = *(const float2*)&sS[k * TPAD + n2];
        float2 pv = *(const float2*)&sP[k * TPAD + n2];
        float4 wg = *(const float4*)&sWg[k * DD + col4];
        float4 wb = *(const float4*)&sWb[k * DD + col4];
        acc1[0][0] += sv.x * wg.x; acc1[0][1] += sv.x * wg.y;
        acc1[0][2] += sv.x * wg.z; acc1[0][3] += sv.x * wg.w;
        acc1[1][0] += sv.y * wg.x; acc1[1][1] += sv.y * wg.y;
        acc1[1][2] += sv.y * wg.z; acc1[1][3] += sv.y * wg.w;
        acc2[0][0] += pv.x * wb.x; acc2[0][1] += pv.x * wb.y;
        acc2[0][2] += pv.x * wb.z; acc2[0][3] += pv.x * wb.w;
        acc2[1][0] += pv.y * wb.x; acc2[1][1] += pv.y * wb.y;
        acc2[1][2] += pv.y * wb.z; acc2[1][3] += pv.y * wb.w;
    }

    float4 bg = *(const float4*)&bgc[col4];
    float4 bb = *(const float4*)&bbi[col4];
#pragma unroll
    for (int a = 0; a < 2; ++a) {
        int node = base + n2 + a;
        if (node < n) {
            float4 o;
            o.x = leaky(acc1[a][0] + bg.x) + leaky(acc2[a][0] + bb.x);
            o.y = leaky(acc1[a][1] + bg.y) + leaky(acc2[a][1] + bb.y);
            o.z = leaky(acc1[a][2] + bg.z) + leaky(acc2[a][2] + bb.z);
            o.w = leaky(acc1[a][3] + bg.w) + leaky(acc2[a][3] + bb.w);
            *(float4*)&ego[node * DD + col4] = o;
            ushort4 ob;
            ob.x = f2bf(o.x); ob.y = f2bf(o.y); ob.z = f2bf(o.z); ob.w = f2bf(o.w);
            egob[node * 16 + (col4 >> 2)] = ob;
        }
    }
}

__global__ void gather_kernel(const float* __restrict__ ego, const int* __restrict__ u,
                              const int* __restrict__ ii, const int* __restrict__ jj,
                              float* __restrict__ out, int layer, int B, int n_users,
                              int normalize) {
    int wid = (blockIdx.x * blockDim.x + threadIdx.x) >> 6;
    int lane = threadIdx.x & 63;
    if (wid >= 3 * B) return;
    int arr = wid / B;
    int b = wid - arr * B;
    int node = (arr == 0) ? u[b] : ((arr == 1) ? n_users + ii[b] : n_users + jj[b]);
    float v = ego[node * DD + lane];
    if (normalize) {
        float ss = v * v;
#pragma unroll
        for (int m = 32; m; m >>= 1) ss += __shfl_xor(ss, m, 64);
        v /= fmaxf(sqrtf(ss), 1e-12f);
    }
    out[wid * 256 + layer * DD + lane] = v;
}

extern "C" void kernel_launch(void* const* d_in, const int* in_sizes, int n_in,
                              void* d_out, int out_size, void* d_ws, size_t ws_size,
                              hipStream_t stream) {
    const float* user_emb = (const float*)d_in[0];
    const float* item_emb = (const float*)d_in[1];
    const float* W_gc = (const float*)d_in[2];
    const float* b_gc = (const float*)d_in[3];
    const float* W_bi = (const float*)d_in[4];
    const float* b_bi = (const float*)d_in[5];
    const float* adj_vals = (const float*)d_in[6];
    const int* adj_rows = (const int*)d_in[7];
    const int* adj_cols = (const int*)d_in[8];
    const int* u = (const int*)d_in[9];
    const int* ii = (const int*)d_in[10];
    const int* jj = (const int*)d_in[11];
    float* out = (float*)d_out;

    const int D = DD;
    int n_users = in_sizes[0] / D;
    int n_items = in_sizes[1] / D;
    int n = n_users + n_items;
    int nnz = in_sizes[6];
    int B = in_sizes[9];
    int L = in_sizes[2] / (D * D);

    int nbuckets = (n + RB - 1) / RB;      // 586
    int flat = nbuckets * NBLKA;

    char* ws = (char*)d_ws;
    auto alloc = [&](size_t bytes) {
        char* p = ws;
        ws += (bytes + 255) & ~(size_t)255;
        return p;
    };
    float* ego = (float*)alloc((size_t)n * D * 4);
    ushort4* egob = (ushort4*)alloc((size_t)n * D * 2);
    float* side = (float*)alloc((size_t)n * D * 4);
    int* counts_t = (int*)alloc((size_t)flat * 4);
    int* offsets = (int*)alloc((size_t)(flat + 1) * 4);
    int* blocksums = (int*)alloc(4096);
    int2* csr_cv = (int2*)alloc((size_t)nnz * 8);
    int2* sorted_cv = (int2*)alloc((size_t)nnz * 8);
    int* rowoff = (int*)alloc((size_t)(nbuckets * RB + 1) * 4);
    int4* ovf = (int4*)alloc((size_t)OVFCAP * 16);
    int* ovf_cnt = (int*)alloc(256);

    // 1. ego = concat(user_emb, item_emb), fp32 + bf16 mirror
    int total4 = n * D / 4, nu4 = n_users * D / 4;
    concat_kernel<<<(total4 + 255) / 256, 256, 0, stream>>>(
        (const float4*)user_emb, (const float4*)item_emb, (float4*)ego, egob, nu4, total4);

    // 2. layer-0 slice of the output (raw ego, no normalization)
    int grows = 3 * B;
    gather_kernel<<<(grows + 3) / 4, 256, 0, stream>>>(ego, u, ii, jj, out, 0, B, n_users, 0);

    // 3. bucketed CSR build + ONE row-sort (graph identical across layers)
    hipMemsetAsync(ovf_cnt, 0, 4, stream);
    bhist_kernel<<<NBLKA, 256, 0, stream>>>(adj_rows, counts_t, nnz, nbuckets);
    int nblk1 = (flat + 1023) / 1024;
    scan1_kernel<<<nblk1, 1024, 0, stream>>>(counts_t, offsets, blocksums, flat, nbuckets);
    scan2_kernel<<<1, 1024, 0, stream>>>(blocksums, nblk1);
    scan3_kernel<<<nblk1, 1024, 0, stream>>>(offsets, blocksums, flat);
    bscatter_kernel<<<NBLKA, 256, 0, stream>>>(adj_rows, adj_cols, adj_vals, offsets, csr_cv,
                                               nnz, nbuckets);
    sort_kernel<<<nbuckets, 256, 0, stream>>>(offsets, csr_cv, sorted_cv, rowoff, ovf, ovf_cnt,
                                              nnz, nbuckets);

    // 4. layers
    int spmm_waves = (n + 7) / 8;
    int spmm_blocks = (spmm_waves * 64 + 255) / 256;
    for (int l = 0; l < L; ++l) {
        spmm_csr_kernel<<<spmm_blocks, 256, 0, stream>>>(
            (const uint4*)egob, rowoff, sorted_cv, (float4*)side, n);
        ovf_fix_kernel<<<64, 256, 0, stream>>>(ovf, ovf_cnt, ego, side);
        transform_kernel<<<(n + 31) / 32, 256, 0, stream>>>(
            side, ego, egob, W_gc + (size_t)l * D * D, b_gc + (size_t)l * D,
            W_bi + (size_t)l * D * D, b_bi + (size_t)l * D, n);
        gather_kernel<<<(grows + 3) / 4, 256, 0, stream>>>(ego, u, ii, jj, out, l + 1, B,
                                                           n_users, 1);
    }
}

// Round 9
// 511.716 us; speedup vs baseline: 1.4573x; 1.2454x over previous
//
#include <hip/hip_runtime.h>

#define DD 64
#define RB 256         // rows per bucket
#define RB_SHIFT 8
#define CAP 4608       // LDS-sorted edge capacity per bucket (avg 4096, +8 sigma)
#define NBLKA 512      // blocks in the two bucketing passes (pow2; must match)
#define NBLKA_SHIFT 9
#define BMAX 1024      // max buckets (n <= BMAX*RB, col fits 18 bits)
#define COLM 0x3FFFF
#define OVFCAP 65536   // overflow edge list capacity (correctness-only path)
#define WT_STRIDE 80   // padded k-stride of transposed bf16 W in LDS (16B-aligned rows)

typedef __attribute__((ext_vector_type(8))) short bf16x8;
typedef __attribute__((ext_vector_type(4))) float f32x4;

static __device__ __forceinline__ float leaky(float x) {
    return x > 0.f ? x : 0.2f * x;
}

// fp32 -> bf16 bits, round-to-nearest-even
static __device__ __forceinline__ unsigned short f2bf(float f) {
    unsigned u = __float_as_uint(f);
    unsigned r = 0x7FFFu + ((u >> 16) & 1u);
    return (unsigned short)((u + r) >> 16);
}
#define BF_LO(w) __int_as_float((int)((w) << 16))
#define BF_HI(w) __int_as_float((int)((w) & 0xFFFF0000u))

static __device__ __forceinline__ bf16x8 pack8(float a, float b, float c, float d,
                                               float e, float f, float g, float h) {
    bf16x8 r;
    r[0] = (short)f2bf(a); r[1] = (short)f2bf(b); r[2] = (short)f2bf(c); r[3] = (short)f2bf(d);
    r[4] = (short)f2bf(e); r[5] = (short)f2bf(f); r[6] = (short)f2bf(g); r[7] = (short)f2bf(h);
    return r;
}

__global__ void concat_kernel(const float4* __restrict__ ue, const float4* __restrict__ ie,
                              float4* __restrict__ ego, ushort4* __restrict__ egob,
                              int n_user4, int total4) {
    int idx = blockIdx.x * blockDim.x + threadIdx.x;
    if (idx >= total4) return;
    float4 v = (idx < n_user4) ? ue[idx] : ie[idx - n_user4];
    ego[idx] = v;
    ushort4 b;
    b.x = f2bf(v.x); b.y = f2bf(v.y); b.z = f2bf(v.z); b.w = f2bf(v.w);
    egob[idx] = b;
}

// pass A: per-(bucket, block) histogram via LDS — no global atomics.
__global__ void bhist_kernel(const int* __restrict__ rows, int* __restrict__ counts_t, int nnz,
                             int nbuckets) {
    __shared__ int h[BMAX];
    int tid = threadIdx.x, blk = blockIdx.x;
    for (int i = tid; i < nbuckets; i += 256) h[i] = 0;
    __syncthreads();
    int chunk = (nnz + NBLKA - 1) / NBLKA;
    int lo = blk * chunk, hi = min(nnz, lo + chunk);
    for (int e = lo + tid; e < hi; e += 256) atomicAdd(&h[rows[e] >> RB_SHIFT], 1);
    __syncthreads();
    for (int i = tid; i < nbuckets; i += 256) counts_t[blk * nbuckets + i] = h[i];
}

// scan over flat order f = bucket*NBLKA + blk, reading transposed counts.
__global__ void scan1_kernel(const int* __restrict__ counts_t, int* __restrict__ offsets,
                             int* __restrict__ blocksums, int flat, int nbuckets) {
    __shared__ int tmp[1024];
    int t = threadIdx.x;
    int g = blockIdx.x * 1024 + t;
    int x = 0;
    if (g < flat) {
        int i = g >> NBLKA_SHIFT, blk = g & (NBLKA - 1);
        x = counts_t[blk * nbuckets + i];
    }
    tmp[t] = x;
    __syncthreads();
    for (int off = 1; off < 1024; off <<= 1) {
        int y = (t >= off) ? tmp[t - off] : 0;
        __syncthreads();
        tmp[t] += y;
        __syncthreads();
    }
    if (g < flat) offsets[g + 1] = tmp[t];
    if (t == 1023) blocksums[blockIdx.x] = tmp[t];
    if (g == 0) offsets[0] = 0;
}

__global__ void scan2_kernel(int* blocksums, int nb) {
    __shared__ int tmp[1024];
    int t = threadIdx.x;
    int v = (t < nb) ? blocksums[t] : 0;
    tmp[t] = v;
    __syncthreads();
    for (int off = 1; off < 1024; off <<= 1) {
        int y = (t >= off) ? tmp[t - off] : 0;
        __syncthreads();
        tmp[t] += y;
        __syncthreads();
    }
    if (t < nb) blocksums[t] = tmp[t] - v;  // exclusive base per block
}

__global__ void scan3_kernel(int* __restrict__ offsets, const int* __restrict__ blocksums,
                             int n) {
    int g = blockIdx.x * 1024 + threadIdx.x;
    if (g < n) offsets[g + 1] += blocksums[blockIdx.x];
}

// pass B: write each edge into its block-private contiguous slot range per bucket.
__global__ void bscatter_kernel(const int* __restrict__ rows, const int* __restrict__ cols,
                                const float* __restrict__ vals, const int* __restrict__ offsets,
                                int2* __restrict__ csr_cv, int nnz, int nbuckets) {
    __shared__ int cur[BMAX];
    int tid = threadIdx.x, blk = blockIdx.x;
    for (int i = tid; i < nbuckets; i += 256) cur[i] = offsets[i * NBLKA + blk];
    __syncthreads();
    int chunk = (nnz + NBLKA - 1) / NBLKA;
    int lo = blk * chunk, hi = min(nnz, lo + chunk);
    for (int e = lo + tid; e < hi; e += 256) {
        int r = rows[e];
        int p = atomicAdd(&cur[r >> RB_SHIFT], 1);
        int2 cv;
        cv.x = ((r & (RB - 1)) << 18) | cols[e];  // row_low(8b) | col(18b)
        cv.y = __float_as_int(vals[e]);
        csr_cv[p] = cv;
    }
}

// ONE-TIME sort: per bucket, counting-sort edges by row in LDS, write back to
// global (coalesced) and emit full per-row CSR rowoff.
__global__ void __launch_bounds__(256) sort_kernel(
    const int* __restrict__ offsets, const int2* __restrict__ csr_cv,
    int2* __restrict__ sorted_cv, int* __restrict__ rowoff_g,
    int4* __restrict__ ovf, int* __restrict__ ovf_cnt, int nnz, int nbuckets) {
    __shared__ int2 sorted[CAP];
    __shared__ int hist[RB];
    __shared__ int rowoff[RB + 1];
    __shared__ int cur[RB];
    int tid = threadIdx.x;
    int b = blockIdx.x;
    int s = offsets[b * NBLKA];
    int e = offsets[(b + 1) * NBLKA];
    int m = min(e - s, CAP);

    hist[tid] = 0;
    __syncthreads();
    for (int k = s + tid; k < s + m; k += 256)
        atomicAdd(&hist[((unsigned)csr_cv[k].x) >> 18], 1);
    __syncthreads();
    for (int off = 1; off < RB; off <<= 1) {
        int v = (tid >= off) ? hist[tid - off] : 0;
        __syncthreads();
        hist[tid] += v;
        __syncthreads();
    }
    rowoff[tid + 1] = hist[tid];
    if (tid == 0) rowoff[0] = 0;
    __syncthreads();
    cur[tid] = rowoff[tid];
    __syncthreads();
    for (int k = s + tid; k < s + m; k += 256) {
        int2 cv = csr_cv[k];
        int p = atomicAdd(&cur[((unsigned)cv.x) >> 18], 1);
        sorted[p] = cv;
    }
    __syncthreads();
    for (int k = tid; k < m; k += 256) sorted_cv[s + k] = sorted[k];
    rowoff_g[b * RB + tid] = s + rowoff[tid];
    if (b == 0 && tid == 0) rowoff_g[nbuckets * RB] = nnz;
    // overflow (statistically never: CAP = avg + 8 sigma) -> global list
    for (int k = s + CAP + tid; k < e; k += 256) {
        int2 cv = csr_cv[k];
        int p = atomicAdd(ovf_cnt, 1);
        if (p < OVFCAP) {
            int4 o;
            o.x = b * RB + (int)(((unsigned)cv.x) >> 18);
            o.y = cv.x & COLM;
            o.z = cv.y;
            o.w = 0;
            ovf[p] = o;
        }
    }
}

// SpMM over pre-sorted CSR, bf16 gather operand (fp32 vals + fp32 accumulate).
// 8 rows/wave, 8 lanes/row, uint4(= 8 bf16)/lane; fp32 side output.
__global__ void spmm_csr_kernel(const uint4* __restrict__ egob4,
                                const int* __restrict__ rowoff,
                                const int2* __restrict__ sorted_cv,
                                float4* __restrict__ side4, int n) {
    int wid = (blockIdx.x * blockDim.x + threadIdx.x) >> 6;
    int lane = threadIdx.x & 63;
    int sub = lane >> 3, l8 = lane & 7;
    int row = wid * 8 + sub;
    if (row >= n) return;
    int s = rowoff[row], e = rowoff[row + 1];
    float acc[8] = {0.f, 0.f, 0.f, 0.f, 0.f, 0.f, 0.f, 0.f};
    int k = s;
    for (; k + 4 <= e; k += 4) {
        int2 c0 = sorted_cv[k];
        int2 c1 = sorted_cv[k + 1];
        int2 c2 = sorted_cv[k + 2];
        int2 c3 = sorted_cv[k + 3];
        uint4 g0 = egob4[(c0.x & COLM) * 8 + l8];
        uint4 g1 = egob4[(c1.x & COLM) * 8 + l8];
        uint4 g2 = egob4[(c2.x & COLM) * 8 + l8];
        uint4 g3 = egob4[(c3.x & COLM) * 8 + l8];
        float v0 = __int_as_float(c0.y), v1 = __int_as_float(c1.y);
        float v2 = __int_as_float(c2.y), v3 = __int_as_float(c3.y);
        acc[0] += v0 * BF_LO(g0.x); acc[1] += v0 * BF_HI(g0.x);
        acc[2] += v0 * BF_LO(g0.y); acc[3] += v0 * BF_HI(g0.y);
        acc[4] += v0 * BF_LO(g0.z); acc[5] += v0 * BF_HI(g0.z);
        acc[6] += v0 * BF_LO(g0.w); acc[7] += v0 * BF_HI(g0.w);
        acc[0] += v1 * BF_LO(g1.x); acc[1] += v1 * BF_HI(g1.x);
        acc[2] += v1 * BF_LO(g1.y); acc[3] += v1 * BF_HI(g1.y);
        acc[4] += v1 * BF_LO(g1.z); acc[5] += v1 * BF_HI(g1.z);
        acc[6] += v1 * BF_LO(g1.w); acc[7] += v1 * BF_HI(g1.w);
        acc[0] += v2 * BF_LO(g2.x); acc[1] += v2 * BF_HI(g2.x);
        acc[2] += v2 * BF_LO(g2.y); acc[3] += v2 * BF_HI(g2.y);
        acc[4] += v2 * BF_LO(g2.z); acc[5] += v2 * BF_HI(g2.z);
        acc[6] += v2 * BF_LO(g2.w); acc[7] += v2 * BF_HI(g2.w);
        acc[0] += v3 * BF_LO(g3.x); acc[1] += v3 * BF_HI(g3.x);
        acc[2] += v3 * BF_LO(g3.y); acc[3] += v3 * BF_HI(g3.y);
        acc[4] += v3 * BF_LO(g3.z); acc[5] += v3 * BF_HI(g3.z);
        acc[6] += v3 * BF_LO(g3.w); acc[7] += v3 * BF_HI(g3.w);
    }
    for (; k < e; ++k) {
        int2 cv = sorted_cv[k];
        uint4 g = egob4[(cv.x & COLM) * 8 + l8];
        float v = __int_as_float(cv.y);
        acc[0] += v * BF_LO(g.x); acc[1] += v * BF_HI(g.x);
        acc[2] += v * BF_LO(g.y); acc[3] += v * BF_HI(g.y);
        acc[4] += v * BF_LO(g.z); acc[5] += v * BF_HI(g.z);
        acc[6] += v * BF_LO(g.w); acc[7] += v * BF_HI(g.w);
    }
    float4 o0 = {acc[0], acc[1], acc[2], acc[3]};
    float4 o1 = {acc[4], acc[5], acc[6], acc[7]};
    side4[row * 16 + l8 * 2] = o0;
    side4[row * 16 + l8 * 2 + 1] = o1;
}

// correctness-only fixup for sort overflow edges (normally ovf_cnt == 0)
__global__ void ovf_fix_kernel(const int4* __restrict__ ovf, const int* __restrict__ ovf_cnt,
                               const float* __restrict__ ego, float* __restrict__ side) {
    int total = min(*ovf_cnt, OVFCAP);
    for (int i = blockIdx.x * blockDim.x + threadIdx.x; i < total * DD;
         i += gridDim.x * blockDim.x) {
        int e = i >> 6, d = i & 63;
        int4 o = ovf[e];
        atomicAdd(&side[o.x * DD + d], __int_as_float(o.z) * ego[o.y * DD + d]);
    }
}

// MFMA transform: ego_new = leaky(side@Wgc+bgc) + leaky((ego*side)@Wbi+bbi).
// R8 analysis: the fp32 LDS-tile version was LDS-pipe-bound (40 LDS-cyc per
// 16 FMAs; 4688 blk x 64 k x 160 cyc / 256 CU = 78 us = measured 80).
// MFMA needs 0.125 B/MAC: one 16-node tile per wave; A-frags (side, ego*side)
// built from global fp32 loads in fragment layout (A[m=lane&15][k=quad*8+j],
// m120); B = W^T bf16 in LDS (one b128 per frag); C epilogue col=lane&15,
// row=quad*4+reg (m89). fp32 accumulate.
__global__ void __launch_bounds__(256) transform_kernel(
    const float* __restrict__ side, float* __restrict__ ego, ushort* __restrict__ egob,
    const float* __restrict__ Wgc, const float* __restrict__ bgc,
    const float* __restrict__ Wbi, const float* __restrict__ bbi, int n) {
    __shared__ __align__(16) ushort sWg[DD * WT_STRIDE];
    __shared__ __align__(16) ushort sWb[DD * WT_STRIDE];
    int tid = threadIdx.x;
    // stage W transposed bf16: sW[c][k] = W[k][c]
    for (int idx = tid; idx < DD * DD; idx += 256) {
        int k = idx >> 6, c = idx & 63;
        sWg[c * WT_STRIDE + k] = f2bf(Wgc[idx]);
        sWb[c * WT_STRIDE + k] = f2bf(Wbi[idx]);
    }
    __syncthreads();

    int wave = tid >> 6, lane = tid & 63;
    int ntiles = (n + 15) >> 4;
    int tile = blockIdx.x * 4 + wave;
    if (tile >= ntiles) return;
    int base = tile * 16;
    int m = lane & 15, quad = lane >> 4;
    int row = base + m;
    if (row >= n) row = n - 1;

    // A-frags: k_lo = quad*8+j, k_hi = 32+quad*8+j
    const float4* srow = (const float4*)(side + (size_t)row * DD);
    const float4* erow = (const float4*)(ego + (size_t)row * DD);
    float4 s0 = srow[quad * 2], s1 = srow[quad * 2 + 1];
    float4 s2 = srow[8 + quad * 2], s3 = srow[8 + quad * 2 + 1];
    float4 e0 = erow[quad * 2], e1 = erow[quad * 2 + 1];
    float4 e2 = erow[8 + quad * 2], e3 = erow[8 + quad * 2 + 1];

    bf16x8 aS_lo = pack8(s0.x, s0.y, s0.z, s0.w, s1.x, s1.y, s1.z, s1.w);
    bf16x8 aS_hi = pack8(s2.x, s2.y, s2.z, s2.w, s3.x, s3.y, s3.z, s3.w);
    bf16x8 aP_lo = pack8(e0.x * s0.x, e0.y * s0.y, e0.z * s0.z, e0.w * s0.w,
                         e1.x * s1.x, e1.y * s1.y, e1.z * s1.z, e1.w * s1.w);
    bf16x8 aP_hi = pack8(e2.x * s2.x, e2.y * s2.y, e2.z * s2.z, e2.w * s2.w,
                         e3.x * s3.x, e3.y * s3.y, e3.z * s3.z, e3.w * s3.w);

    f32x4 accG[4], accB[4];
#pragma unroll
    for (int ct = 0; ct < 4; ++ct) {
        accG[ct] = (f32x4){0.f, 0.f, 0.f, 0.f};
        accB[ct] = (f32x4){0.f, 0.f, 0.f, 0.f};
    }
#pragma unroll
    for (int ct = 0; ct < 4; ++ct) {
        int col = ct * 16 + m;
        bf16x8 bg_lo = *(const bf16x8*)&sWg[col * WT_STRIDE + quad * 8];
        bf16x8 bg_hi = *(const bf16x8*)&sWg[col * WT_STRIDE + 32 + quad * 8];
        bf16x8 bb_lo = *(const bf16x8*)&sWb[col * WT_STRIDE + quad * 8];
        bf16x8 bb_hi = *(const bf16x8*)&sWb[col * WT_STRIDE + 32 + quad * 8];
        accG[ct] = __builtin_amdgcn_mfma_f32_16x16x32_bf16(aS_lo, bg_lo, accG[ct], 0, 0, 0);
        accG[ct] = __builtin_amdgcn_mfma_f32_16x16x32_bf16(aS_hi, bg_hi, accG[ct], 0, 0, 0);
        accB[ct] = __builtin_amdgcn_mfma_f32_16x16x32_bf16(aP_lo, bb_lo, accB[ct], 0, 0, 0);
        accB[ct] = __builtin_amdgcn_mfma_f32_16x16x32_bf16(aP_hi, bb_hi, accB[ct], 0, 0, 0);
    }

#pragma unroll
    for (int ct = 0; ct < 4; ++ct) {
        int col = ct * 16 + m;
        float bg = bgc[col], bb = bbi[col];
#pragma unroll
        for (int r = 0; r < 4; ++r) {
            int node = base + quad * 4 + r;
            if (node < n) {
                float o = leaky(accG[ct][r] + bg) + leaky(accB[ct][r] + bb);
                ego[(size_t)node * DD + col] = o;
                egob[(size_t)node * DD + col] = f2bf(o);
            }
        }
    }
}

__global__ void gather_kernel(const float* __restrict__ ego, const int* __restrict__ u,
                              const int* __restrict__ ii, const int* __restrict__ jj,
                              float* __restrict__ out, int layer, int B, int n_users,
                              int normalize) {
    int wid = (blockIdx.x * blockDim.x + threadIdx.x) >> 6;
    int lane = threadIdx.x & 63;
    if (wid >= 3 * B) return;
    int arr = wid / B;
    int b = wid - arr * B;
    int node = (arr == 0) ? u[b] : ((arr == 1) ? n_users + ii[b] : n_users + jj[b]);
    float v = ego[node * DD + lane];
    if (normalize) {
        float ss = v * v;
#pragma unroll
        for (int m = 32; m; m >>= 1) ss += __shfl_xor(ss, m, 64);
        v /= fmaxf(sqrtf(ss), 1e-12f);
    }
    out[wid * 256 + layer * DD + lane] = v;
}

extern "C" void kernel_launch(void* const* d_in, const int* in_sizes, int n_in,
                              void* d_out, int out_size, void* d_ws, size_t ws_size,
                              hipStream_t stream) {
    const float* user_emb = (const float*)d_in[0];
    const float* item_emb = (const float*)d_in[1];
    const float* W_gc = (const float*)d_in[2];
    const float* b_gc = (const float*)d_in[3];
    const float* W_bi = (const float*)d_in[4];
    const float* b_bi = (const float*)d_in[5];
    const float* adj_vals = (const float*)d_in[6];
    const int* adj_rows = (const int*)d_in[7];
    const int* adj_cols = (const int*)d_in[8];
    const int* u = (const int*)d_in[9];
    const int* ii = (const int*)d_in[10];
    const int* jj = (const int*)d_in[11];
    float* out = (float*)d_out;

    const int D = DD;
    int n_users = in_sizes[0] / D;
    int n_items = in_sizes[1] / D;
    int n = n_users + n_items;
    int nnz = in_sizes[6];
    int B = in_sizes[9];
    int L = in_sizes[2] / (D * D);

    int nbuckets = (n + RB - 1) / RB;      // 586
    int flat = nbuckets * NBLKA;

    char* ws = (char*)d_ws;
    auto alloc = [&](size_t bytes) {
        char* p = ws;
        ws += (bytes + 255) & ~(size_t)255;
        return p;
    };
    float* ego = (float*)alloc((size_t)n * D * 4);
    ushort* egob = (ushort*)alloc((size_t)n * D * 2);
    float* side = (float*)alloc((size_t)n * D * 4);
    int* counts_t = (int*)alloc((size_t)flat * 4);
    int* offsets = (int*)alloc((size_t)(flat + 1) * 4);
    int* blocksums = (int*)alloc(4096);
    int2* csr_cv = (int2*)alloc((size_t)nnz * 8);
    int2* sorted_cv = (int2*)alloc((size_t)nnz * 8);
    int* rowoff = (int*)alloc((size_t)(nbuckets * RB + 1) * 4);
    int4* ovf = (int4*)alloc((size_t)OVFCAP * 16);
    int* ovf_cnt = (int*)alloc(256);

    // 1. ego = concat(user_emb, item_emb), fp32 + bf16 mirror
    int total4 = n * D / 4, nu4 = n_users * D / 4;
    concat_kernel<<<(total4 + 255) / 256, 256, 0, stream>>>(
        (const float4*)user_emb, (const float4*)item_emb, (float4*)ego, (ushort4*)egob,
        nu4, total4);

    // 2. layer-0 slice of the output (raw ego, no normalization)
    int grows = 3 * B;
    gather_kernel<<<(grows + 3) / 4, 256, 0, stream>>>(ego, u, ii, jj, out, 0, B, n_users, 0);

    // 3. bucketed CSR build + ONE row-sort (graph identical across layers)
    hipMemsetAsync(ovf_cnt, 0, 4, stream);
    bhist_kernel<<<NBLKA, 256, 0, stream>>>(adj_rows, counts_t, nnz, nbuckets);
    int nblk1 = (flat + 1023) / 1024;
    scan1_kernel<<<nblk1, 1024, 0, stream>>>(counts_t, offsets, blocksums, flat, nbuckets);
    scan2_kernel<<<1, 1024, 0, stream>>>(blocksums, nblk1);
    scan3_kernel<<<nblk1, 1024, 0, stream>>>(offsets, blocksums, flat);
    bscatter_kernel<<<NBLKA, 256, 0, stream>>>(adj_rows, adj_cols, adj_vals, offsets, csr_cv,
                                               nnz, nbuckets);
    sort_kernel<<<nbuckets, 256, 0, stream>>>(offsets, csr_cv, sorted_cv, rowoff, ovf, ovf_cnt,
                                              nnz, nbuckets);

    // 4. layers
    int spmm_waves = (n + 7) / 8;
    int spmm_blocks = (spmm_waves * 64 + 255) / 256;
    int ntiles = (n + 15) / 16;
    for (int l = 0; l < L; ++l) {
        spmm_csr_kernel<<<spmm_blocks, 256, 0, stream>>>(
            (const uint4*)egob, rowoff, sorted_cv, (float4*)side, n);
        ovf_fix_kernel<<<64, 256, 0, stream>>>(ovf, ovf_cnt, ego, side);
        transform_kernel<<<(ntiles + 3) / 4, 256, 0, stream>>>(
            side, ego, egob, W_gc + (size_t)l * D * D, b_gc + (size_t)l * D,
            W_bi + (size_t)l * D * D, b_bi + (size_t)l * D, n);
        gather_kernel<<<(grows + 3) / 4, 256, 0, stream>>>(ego, u, ii, jj, out, l + 1, B,
                                                           n_users, 1);
    }
}

// Round 10
// 496.181 us; speedup vs baseline: 1.5029x; 1.0313x over previous
//
#include <hip/hip_runtime.h>

#define DD 64
#define RB 256         // rows per bucket
#define RB_SHIFT 8
#define CAP 4608       // LDS-sorted edge capacity per bucket (avg 4096, +8 sigma)
#define NBLKA 512      // blocks in the two bucketing passes (pow2; must match)
#define NBLKA_SHIFT 9
#define BMAX 1024      // max buckets (n <= BMAX*RB, col fits 18 bits)
#define COLM 0x3FFFF
#define OVFCAP 65536   // overflow edge list capacity (correctness-only path)
#define WT_STRIDE 80   // padded k-stride of transposed bf16 W in LDS (16B-aligned rows)
#define EMAX 4704      // per-sub-chunk LDS edge buffer in bscatter

typedef __attribute__((ext_vector_type(8))) short bf16x8;
typedef __attribute__((ext_vector_type(4))) float f32x4;

static __device__ __forceinline__ float leaky(float x) {
    return x > 0.f ? x : 0.2f * x;
}

// fp32 -> bf16 bits, round-to-nearest-even
static __device__ __forceinline__ unsigned short f2bf(float f) {
    unsigned u = __float_as_uint(f);
    unsigned r = 0x7FFFu + ((u >> 16) & 1u);
    return (unsigned short)((u + r) >> 16);
}
#define BF_LO(w) __int_as_float((int)((w) << 16))
#define BF_HI(w) __int_as_float((int)((w) & 0xFFFF0000u))

static __device__ __forceinline__ bf16x8 pack8(float a, float b, float c, float d,
                                               float e, float f, float g, float h) {
    bf16x8 r;
    r[0] = (short)f2bf(a); r[1] = (short)f2bf(b); r[2] = (short)f2bf(c); r[3] = (short)f2bf(d);
    r[4] = (short)f2bf(e); r[5] = (short)f2bf(f); r[6] = (short)f2bf(g); r[7] = (short)f2bf(h);
    return r;
}

__global__ void concat_kernel(const float4* __restrict__ ue, const float4* __restrict__ ie,
                              float4* __restrict__ ego, ushort4* __restrict__ egob,
                              int n_user4, int total4) {
    int idx = blockIdx.x * blockDim.x + threadIdx.x;
    if (idx >= total4) return;
    float4 v = (idx < n_user4) ? ue[idx] : ie[idx - n_user4];
    ego[idx] = v;
    ushort4 b;
    b.x = f2bf(v.x); b.y = f2bf(v.y); b.z = f2bf(v.z); b.w = f2bf(v.w);
    egob[idx] = b;
}

// pass A: per-(bucket, block) histogram via LDS — no global atomics.
__global__ void bhist_kernel(const int* __restrict__ rows, int* __restrict__ counts_t, int nnz,
                             int nbuckets) {
    __shared__ int h[BMAX];
    int tid = threadIdx.x, blk = blockIdx.x;
    for (int i = tid; i < nbuckets; i += 256) h[i] = 0;
    __syncthreads();
    int chunk = (nnz + NBLKA - 1) / NBLKA;
    int lo = blk * chunk, hi = min(nnz, lo + chunk);
    for (int e = lo + tid; e < hi; e += 256) atomicAdd(&h[rows[e] >> RB_SHIFT], 1);
    __syncthreads();
    for (int i = tid; i < nbuckets; i += 256) counts_t[blk * nbuckets + i] = h[i];
}

// scan over flat order f = bucket*NBLKA + blk, reading transposed counts.
__global__ void scan1_kernel(const int* __restrict__ counts_t, int* __restrict__ offsets,
                             int* __restrict__ blocksums, int flat, int nbuckets) {
    __shared__ int tmp[1024];
    int t = threadIdx.x;
    int g = blockIdx.x * 1024 + t;
    int x = 0;
    if (g < flat) {
        int i = g >> NBLKA_SHIFT, blk = g & (NBLKA - 1);
        x = counts_t[blk * nbuckets + i];
    }
    tmp[t] = x;
    __syncthreads();
    for (int off = 1; off < 1024; off <<= 1) {
        int y = (t >= off) ? tmp[t - off] : 0;
        __syncthreads();
        tmp[t] += y;
        __syncthreads();
    }
    if (g < flat) offsets[g + 1] = tmp[t];
    if (t == 1023) blocksums[blockIdx.x] = tmp[t];
    if (g == 0) offsets[0] = 0;
}

__global__ void scan2_kernel(int* blocksums, int nb) {
    __shared__ int tmp[1024];
    int t = threadIdx.x;
    int v = (t < nb) ? blocksums[t] : 0;
    tmp[t] = v;
    __syncthreads();
    for (int off = 1; off < 1024; off <<= 1) {
        int y = (t >= off) ? tmp[t - off] : 0;
        __syncthreads();
        tmp[t] += y;
        __syncthreads();
    }
    if (t < nb) blocksums[t] = tmp[t] - v;  // exclusive base per block
}

__global__ void scan3_kernel(int* __restrict__ offsets, const int* __restrict__ blocksums,
                             int n) {
    int g = blockIdx.x * 1024 + threadIdx.x;
    if (g < n) offsets[g + 1] += blocksums[blockIdx.x];
}

// pass B v2: LDS bucket-sort the block's chunk, then write back with
// consecutive lanes -> consecutive global addresses. R9 counters showed the
// old per-edge scattered 8B stores were transaction-bound (~14 cyc/store/CU,
// 64 lines touched per wave store). Runs of ~8 edges per (bucket,block)
// segment now coalesce into ~8 transactions per wave.
__global__ void __launch_bounds__(256) bscatter_kernel(
    const int* __restrict__ rows, const int* __restrict__ cols,
    const float* __restrict__ vals, const int* __restrict__ offsets,
    int2* __restrict__ csr_cv, int nnz, int nbuckets) {
    __shared__ int hist[BMAX];
    __shared__ int lbase[BMAX];
    __shared__ int cur[BMAX];
    __shared__ int gcur[BMAX];
    __shared__ int tsum[256];
    __shared__ int2 buf[EMAX];
    __shared__ int dst[EMAX];
    int tid = threadIdx.x, blk = blockIdx.x;
    int chunk = (nnz + NBLKA - 1) / NBLKA;
    int lo = blk * chunk, hi = min(nnz, lo + chunk);
    for (int i = tid; i < BMAX; i += 256)
        gcur[i] = (i < nbuckets) ? offsets[i * NBLKA + blk] : 0;
    for (int sub = lo; sub < hi; sub += EMAX) {  // one iteration for this problem size
        int scount = min(EMAX, hi - sub);
        for (int i = tid; i < BMAX; i += 256) hist[i] = 0;
        __syncthreads();
        for (int e = sub + tid; e < sub + scount; e += 256)
            atomicAdd(&hist[rows[e] >> RB_SHIFT], 1);
        __syncthreads();
        // exclusive scan hist -> lbase (BMAX = 256*4: 4 per thread + block scan)
        int loc[4];
        int s = 0;
        int bi = tid * 4;
#pragma unroll
        for (int j = 0; j < 4; ++j) { loc[j] = s; s += hist[bi + j]; }
        tsum[tid] = s;
        __syncthreads();
        for (int off = 1; off < 256; off <<= 1) {
            int v = (tid >= off) ? tsum[tid - off] : 0;
            __syncthreads();
            tsum[tid] += v;
            __syncthreads();
        }
        int excl = tid ? tsum[tid - 1] : 0;
#pragma unroll
        for (int j = 0; j < 4; ++j) {
            lbase[bi + j] = excl + loc[j];
            cur[bi + j] = excl + loc[j];
        }
        __syncthreads();
        for (int e = sub + tid; e < sub + scount; e += 256) {
            int r = rows[e];
            int b = r >> RB_SHIFT;
            int p = atomicAdd(&cur[b], 1);
            int2 cv;
            cv.x = ((r & (RB - 1)) << 18) | cols[e];  // row_low(8b) | col(18b)
            cv.y = __float_as_int(vals[e]);
            buf[p] = cv;
            dst[p] = gcur[b] + (p - lbase[b]);
        }
        __syncthreads();
        for (int k = tid; k < scount; k += 256) csr_cv[dst[k]] = buf[k];
        __syncthreads();
        for (int i = tid; i < BMAX; i += 256) gcur[i] += hist[i];
        __syncthreads();
    }
}

// ONE-TIME sort: per bucket, counting-sort edges by row in LDS, write back to
// global (coalesced) and emit full per-row CSR rowoff.
__global__ void __launch_bounds__(256) sort_kernel(
    const int* __restrict__ offsets, const int2* __restrict__ csr_cv,
    int2* __restrict__ sorted_cv, int* __restrict__ rowoff_g,
    int4* __restrict__ ovf, int* __restrict__ ovf_cnt, int nnz, int nbuckets) {
    __shared__ int2 sorted[CAP];
    __shared__ int hist[RB];
    __shared__ int rowoff[RB + 1];
    __shared__ int cur[RB];
    int tid = threadIdx.x;
    int b = blockIdx.x;
    int s = offsets[b * NBLKA];
    int e = offsets[(b + 1) * NBLKA];
    int m = min(e - s, CAP);

    hist[tid] = 0;
    __syncthreads();
    for (int k = s + tid; k < s + m; k += 256)
        atomicAdd(&hist[((unsigned)csr_cv[k].x) >> 18], 1);
    __syncthreads();
    for (int off = 1; off < RB; off <<= 1) {
        int v = (tid >= off) ? hist[tid - off] : 0;
        __syncthreads();
        hist[tid] += v;
        __syncthreads();
    }
    rowoff[tid + 1] = hist[tid];
    if (tid == 0) rowoff[0] = 0;
    __syncthreads();
    cur[tid] = rowoff[tid];
    __syncthreads();
    for (int k = s + tid; k < s + m; k += 256) {
        int2 cv = csr_cv[k];
        int p = atomicAdd(&cur[((unsigned)cv.x) >> 18], 1);
        sorted[p] = cv;
    }
    __syncthreads();
    for (int k = tid; k < m; k += 256) sorted_cv[s + k] = sorted[k];
    rowoff_g[b * RB + tid] = s + rowoff[tid];
    if (b == 0 && tid == 0) rowoff_g[nbuckets * RB] = nnz;
    // overflow (statistically never: CAP = avg + 8 sigma) -> global list
    for (int k = s + CAP + tid; k < e; k += 256) {
        int2 cv = csr_cv[k];
        int p = atomicAdd(ovf_cnt, 1);
        if (p < OVFCAP) {
            int4 o;
            o.x = b * RB + (int)(((unsigned)cv.x) >> 18);
            o.y = cv.x & COLM;
            o.z = cv.y;
            o.w = 0;
            ovf[p] = o;
        }
    }
}

// SpMM over pre-sorted CSR, bf16 gather operand (fp32 vals + fp32 accumulate).
// 8 rows/wave, 8 lanes/row, uint4(= 8 bf16)/lane; fp32 side output.
__global__ void spmm_csr_kernel(const uint4* __restrict__ egob4,
                                const int* __restrict__ rowoff,
                                const int2* __restrict__ sorted_cv,
                                float4* __restrict__ side4, int n) {
    int wid = (blockIdx.x * blockDim.x + threadIdx.x) >> 6;
    int lane = threadIdx.x & 63;
    int sub = lane >> 3, l8 = lane & 7;
    int row = wid * 8 + sub;
    if (row >= n) return;
    int s = rowoff[row], e = rowoff[row + 1];
    float acc[8] = {0.f, 0.f, 0.f, 0.f, 0.f, 0.f, 0.f, 0.f};
    int k = s;
    for (; k + 4 <= e; k += 4) {
        int2 c0 = sorted_cv[k];
        int2 c1 = sorted_cv[k + 1];
        int2 c2 = sorted_cv[k + 2];
        int2 c3 = sorted_cv[k + 3];
        uint4 g0 = egob4[(c0.x & COLM) * 8 + l8];
        uint4 g1 = egob4[(c1.x & COLM) * 8 + l8];
        uint4 g2 = egob4[(c2.x & COLM) * 8 + l8];
        uint4 g3 = egob4[(c3.x & COLM) * 8 + l8];
        float v0 = __int_as_float(c0.y), v1 = __int_as_float(c1.y);
        float v2 = __int_as_float(c2.y), v3 = __int_as_float(c3.y);
        acc[0] += v0 * BF_LO(g0.x); acc[1] += v0 * BF_HI(g0.x);
        acc[2] += v0 * BF_LO(g0.y); acc[3] += v0 * BF_HI(g0.y);
        acc[4] += v0 * BF_LO(g0.z); acc[5] += v0 * BF_HI(g0.z);
        acc[6] += v0 * BF_LO(g0.w); acc[7] += v0 * BF_HI(g0.w);
        acc[0] += v1 * BF_LO(g1.x); acc[1] += v1 * BF_HI(g1.x);
        acc[2] += v1 * BF_LO(g1.y); acc[3] += v1 * BF_HI(g1.y);
        acc[4] += v1 * BF_LO(g1.z); acc[5] += v1 * BF_HI(g1.z);
        acc[6] += v1 * BF_LO(g1.w); acc[7] += v1 * BF_HI(g1.w);
        acc[0] += v2 * BF_LO(g2.x); acc[1] += v2 * BF_HI(g2.x);
        acc[2] += v2 * BF_LO(g2.y); acc[3] += v2 * BF_HI(g2.y);
        acc[4] += v2 * BF_LO(g2.z); acc[5] += v2 * BF_HI(g2.z);
        acc[6] += v2 * BF_LO(g2.w); acc[7] += v2 * BF_HI(g2.w);
        acc[0] += v3 * BF_LO(g3.x); acc[1] += v3 * BF_HI(g3.x);
        acc[2] += v3 * BF_LO(g3.y); acc[3] += v3 * BF_HI(g3.y);
        acc[4] += v3 * BF_LO(g3.z); acc[5] += v3 * BF_HI(g3.z);
        acc[6] += v3 * BF_LO(g3.w); acc[7] += v3 * BF_HI(g3.w);
    }
    for (; k < e; ++k) {
        int2 cv = sorted_cv[k];
        uint4 g = egob4[(cv.x & COLM) * 8 + l8];
        float v = __int_as_float(cv.y);
        acc[0] += v * BF_LO(g.x); acc[1] += v * BF_HI(g.x);
        acc[2] += v * BF_LO(g.y); acc[3] += v * BF_HI(g.y);
        acc[4] += v * BF_LO(g.z); acc[5] += v * BF_HI(g.z);
        acc[6] += v * BF_LO(g.w); acc[7] += v * BF_HI(g.w);
    }
    float4 o0 = {acc[0], acc[1], acc[2], acc[3]};
    float4 o1 = {acc[4], acc[5], acc[6], acc[7]};
    side4[row * 16 + l8 * 2] = o0;
    side4[row * 16 + l8 * 2 + 1] = o1;
}

// correctness-only fixup for sort overflow edges (normally ovf_cnt == 0)
__global__ void ovf_fix_kernel(const int4* __restrict__ ovf, const int* __restrict__ ovf_cnt,
                               const float* __restrict__ ego, float* __restrict__ side) {
    int total = min(*ovf_cnt, OVFCAP);
    for (int i = blockIdx.x * blockDim.x + threadIdx.x; i < total * DD;
         i += gridDim.x * blockDim.x) {
        int e = i >> 6, d = i & 63;
        int4 o = ovf[e];
        atomicAdd(&side[o.x * DD + d], __int_as_float(o.z) * ego[o.y * DD + d]);
    }
}

// MFMA transform: ego_new = leaky(side@Wgc+bgc) + leaky((ego*side)@Wbi+bbi).
// One 16-node tile per wave; A-frags from global fp32 in fragment layout;
// B = W^T bf16 in LDS; C epilogue col=lane&15, row=quad*4+reg; fp32 accumulate.
__global__ void __launch_bounds__(256) transform_kernel(
    const float* __restrict__ side, float* __restrict__ ego, ushort* __restrict__ egob,
    const float* __restrict__ Wgc, const float* __restrict__ bgc,
    const float* __restrict__ Wbi, const float* __restrict__ bbi, int n) {
    __shared__ __align__(16) ushort sWg[DD * WT_STRIDE];
    __shared__ __align__(16) ushort sWb[DD * WT_STRIDE];
    int tid = threadIdx.x;
    // stage W transposed bf16: sW[c][k] = W[k][c]
    for (int idx = tid; idx < DD * DD; idx += 256) {
        int k = idx >> 6, c = idx & 63;
        sWg[c * WT_STRIDE + k] = f2bf(Wgc[idx]);
        sWb[c * WT_STRIDE + k] = f2bf(Wbi[idx]);
    }
    __syncthreads();

    int wave = tid >> 6, lane = tid & 63;
    int ntiles = (n + 15) >> 4;
    int tile = blockIdx.x * 4 + wave;
    if (tile >= ntiles) return;
    int base = tile * 16;
    int m = lane & 15, quad = lane >> 4;
    int row = base + m;
    if (row >= n) row = n - 1;

    // A-frags: k_lo = quad*8+j, k_hi = 32+quad*8+j
    const float4* srow = (const float4*)(side + (size_t)row * DD);
    const float4* erow = (const float4*)(ego + (size_t)row * DD);
    float4 s0 = srow[quad * 2], s1 = srow[quad * 2 + 1];
    float4 s2 = srow[8 + quad * 2], s3 = srow[8 + quad * 2 + 1];
    float4 e0 = erow[quad * 2], e1 = erow[quad * 2 + 1];
    float4 e2 = erow[8 + quad * 2], e3 = erow[8 + quad * 2 + 1];

    bf16x8 aS_lo = pack8(s0.x, s0.y, s0.z, s0.w, s1.x, s1.y, s1.z, s1.w);
    bf16x8 aS_hi = pack8(s2.x, s2.y, s2.z, s2.w, s3.x, s3.y, s3.z, s3.w);
    bf16x8 aP_lo = pack8(e0.x * s0.x, e0.y * s0.y, e0.z * s0.z, e0.w * s0.w,
                         e1.x * s1.x, e1.y * s1.y, e1.z * s1.z, e1.w * s1.w);
    bf16x8 aP_hi = pack8(e2.x * s2.x, e2.y * s2.y, e2.z * s2.z, e2.w * s2.w,
                         e3.x * s3.x, e3.y * s3.y, e3.z * s3.z, e3.w * s3.w);

    f32x4 accG[4], accB[4];
#pragma unroll
    for (int ct = 0; ct < 4; ++ct) {
        accG[ct] = (f32x4){0.f, 0.f, 0.f, 0.f};
        accB[ct] = (f32x4){0.f, 0.f, 0.f, 0.f};
    }
#pragma unroll
    for (int ct = 0; ct < 4; ++ct) {
        int col = ct * 16 + m;
        bf16x8 bg_lo = *(const bf16x8*)&sWg[col * WT_STRIDE + quad * 8];
        bf16x8 bg_hi = *(const bf16x8*)&sWg[col * WT_STRIDE + 32 + quad * 8];
        bf16x8 bb_lo = *(const bf16x8*)&sWb[col * WT_STRIDE + quad * 8];
        bf16x8 bb_hi = *(const bf16x8*)&sWb[col * WT_STRIDE + 32 + quad * 8];
        accG[ct] = __builtin_amdgcn_mfma_f32_16x16x32_bf16(aS_lo, bg_lo, accG[ct], 0, 0, 0);
        accG[ct] = __builtin_amdgcn_mfma_f32_16x16x32_bf16(aS_hi, bg_hi, accG[ct], 0, 0, 0);
        accB[ct] = __builtin_amdgcn_mfma_f32_16x16x32_bf16(aP_lo, bb_lo, accB[ct], 0, 0, 0);
        accB[ct] = __builtin_amdgcn_mfma_f32_16x16x32_bf16(aP_hi, bb_hi, accB[ct], 0, 0, 0);
    }

#pragma unroll
    for (int ct = 0; ct < 4; ++ct) {
        int col = ct * 16 + m;
        float bg = bgc[col], bb = bbi[col];
#pragma unroll
        for (int r = 0; r < 4; ++r) {
            int node = base + quad * 4 + r;
            if (node < n) {
                float o = leaky(accG[ct][r] + bg) + leaky(accB[ct][r] + bb);
                ego[(size_t)node * DD + col] = o;
                egob[(size_t)node * DD + col] = f2bf(o);
            }
        }
    }
}

__global__ void gather_kernel(const float* __restrict__ ego, const int* __restrict__ u,
                              const int* __restrict__ ii, const int* __restrict__ jj,
                              float* __restrict__ out, int layer, int B, int n_users,
                              int normalize) {
    int wid = (blockIdx.x * blockDim.x + threadIdx.x) >> 6;
    int lane = threadIdx.x & 63;
    if (wid >= 3 * B) return;
    int arr = wid / B;
    int b = wid - arr * B;
    int node = (arr == 0) ? u[b] : ((arr == 1) ? n_users + ii[b] : n_users + jj[b]);
    float v = ego[node * DD + lane];
    if (normalize) {
        float ss = v * v;
#pragma unroll
        for (int m = 32; m; m >>= 1) ss += __shfl_xor(ss, m, 64);
        v /= fmaxf(sqrtf(ss), 1e-12f);
    }
    out[wid * 256 + layer * DD + lane] = v;
}

extern "C" void kernel_launch(void* const* d_in, const int* in_sizes, int n_in,
                              void* d_out, int out_size, void* d_ws, size_t ws_size,
                              hipStream_t stream) {
    const float* user_emb = (const float*)d_in[0];
    const float* item_emb = (const float*)d_in[1];
    const float* W_gc = (const float*)d_in[2];
    const float* b_gc = (const float*)d_in[3];
    const float* W_bi = (const float*)d_in[4];
    const float* b_bi = (const float*)d_in[5];
    const float* adj_vals = (const float*)d_in[6];
    const int* adj_rows = (const int*)d_in[7];
    const int* adj_cols = (const int*)d_in[8];
    const int* u = (const int*)d_in[9];
    const int* ii = (const int*)d_in[10];
    const int* jj = (const int*)d_in[11];
    float* out = (float*)d_out;

    const int D = DD;
    int n_users = in_sizes[0] / D;
    int n_items = in_sizes[1] / D;
    int n = n_users + n_items;
    int nnz = in_sizes[6];
    int B = in_sizes[9];
    int L = in_sizes[2] / (D * D);

    int nbuckets = (n + RB - 1) / RB;      // 586
    int flat = nbuckets * NBLKA;

    char* ws = (char*)d_ws;
    auto alloc = [&](size_t bytes) {
        char* p = ws;
        ws += (bytes + 255) & ~(size_t)255;
        return p;
    };
    float* ego = (float*)alloc((size_t)n * D * 4);
    ushort* egob = (ushort*)alloc((size_t)n * D * 2);
    float* side = (float*)alloc((size_t)n * D * 4);
    int* counts_t = (int*)alloc((size_t)flat * 4);
    int* offsets = (int*)alloc((size_t)(flat + 1) * 4);
    int* blocksums = (int*)alloc(4096);
    int2* csr_cv = (int2*)alloc((size_t)nnz * 8);
    int2* sorted_cv = (int2*)alloc((size_t)nnz * 8);
    int* rowoff = (int*)alloc((size_t)(nbuckets * RB + 1) * 4);
    int4* ovf = (int4*)alloc((size_t)OVFCAP * 16);
    int* ovf_cnt = (int*)alloc(256);

    // 1. ego = concat(user_emb, item_emb), fp32 + bf16 mirror
    int total4 = n * D / 4, nu4 = n_users * D / 4;
    concat_kernel<<<(total4 + 255) / 256, 256, 0, stream>>>(
        (const float4*)user_emb, (const float4*)item_emb, (float4*)ego, (ushort4*)egob,
        nu4, total4);

    // 2. layer-0 slice of the output (raw ego, no normalization)
    int grows = 3 * B;
    gather_kernel<<<(grows + 3) / 4, 256, 0, stream>>>(ego, u, ii, jj, out, 0, B, n_users, 0);

    // 3. bucketed CSR build + ONE row-sort (graph identical across layers)
    hipMemsetAsync(ovf_cnt, 0, 4, stream);
    bhist_kernel<<<NBLKA, 256, 0, stream>>>(adj_rows, counts_t, nnz, nbuckets);
    int nblk1 = (flat + 1023) / 1024;
    scan1_kernel<<<nblk1, 1024, 0, stream>>>(counts_t, offsets, blocksums, flat, nbuckets);
    scan2_kernel<<<1, 1024, 0, stream>>>(blocksums, nblk1);
    scan3_kernel<<<nblk1, 1024, 0, stream>>>(offsets, blocksums, flat);
    bscatter_kernel<<<NBLKA, 256, 0, stream>>>(adj_rows, adj_cols, adj_vals, offsets, csr_cv,
                                               nnz, nbuckets);
    sort_kernel<<<nbuckets, 256, 0, stream>>>(offsets, csr_cv, sorted_cv, rowoff, ovf, ovf_cnt,
                                              nnz, nbuckets);

    // 4. layers
    int spmm_waves = (n + 7) / 8;
    int spmm_blocks = (spmm_waves * 64 + 255) / 256;
    int ntiles = (n + 15) / 16;
    for (int l = 0; l < L; ++l) {
        spmm_csr_kernel<<<spmm_blocks, 256, 0, stream>>>(
            (const uint4*)egob, rowoff, sorted_cv, (float4*)side, n);
        ovf_fix_kernel<<<64, 256, 0, stream>>>(ovf, ovf_cnt, ego, side);
        transform_kernel<<<(ntiles + 3) / 4, 256, 0, stream>>>(
            side, ego, egob, W_gc + (size_t)l * D * D, b_gc + (size_t)l * D,
            W_bi + (size_t)l * D * D, b_bi + (size_t)l * D, n);
        gather_kernel<<<(grows + 3) / 4, 256, 0, stream>>>(ego, u, ii, jj, out, l + 1, B,
                                                           n_users, 1);
    }
}

// Round 11
// 479.633 us; speedup vs baseline: 1.5548x; 1.0345x over previous
//
#include <hip/hip_runtime.h>

#define DD 64
#define RB 256         // rows per bucket
#define RB_SHIFT 8
#define CAP 4608       // LDS-sorted edge capacity per bucket (avg 4096, +8 sigma)
#define NBLKA 512      // blocks in the two bucketing passes (pow2; must match)
#define NBLKA_SHIFT 9
#define BMAX 1024      // max buckets (n <= BMAX*RB, col fits 18 bits)
#define COLM 0x3FFFF
#define WT_STRIDE 80   // padded k-stride of transposed bf16 W in LDS (16B-aligned rows)
#define EMAX 4704      // per-sub-chunk LDS edge buffer in bscatter
#define SPAD 68        // padded fp32 stride of the LDS side tile (2-way max on frag reads)

typedef __attribute__((ext_vector_type(8))) short bf16x8;
typedef __attribute__((ext_vector_type(4))) float f32x4;

static __device__ __forceinline__ float leaky(float x) {
    return x > 0.f ? x : 0.2f * x;
}

// fp32 -> bf16 bits, round-to-nearest-even
static __device__ __forceinline__ unsigned short f2bf(float f) {
    unsigned u = __float_as_uint(f);
    unsigned r = 0x7FFFu + ((u >> 16) & 1u);
    return (unsigned short)((u + r) >> 16);
}
#define BF_LO(w) __int_as_float((int)((w) << 16))
#define BF_HI(w) __int_as_float((int)((w) & 0xFFFF0000u))

static __device__ __forceinline__ bf16x8 pack8(float a, float b, float c, float d,
                                               float e, float f, float g, float h) {
    bf16x8 r;
    r[0] = (short)f2bf(a); r[1] = (short)f2bf(b); r[2] = (short)f2bf(c); r[3] = (short)f2bf(d);
    r[4] = (short)f2bf(e); r[5] = (short)f2bf(f); r[6] = (short)f2bf(g); r[7] = (short)f2bf(h);
    return r;
}

__global__ void concat_kernel(const float4* __restrict__ ue, const float4* __restrict__ ie,
                              float4* __restrict__ ego, ushort4* __restrict__ egob,
                              int n_user4, int total4) {
    int idx = blockIdx.x * blockDim.x + threadIdx.x;
    if (idx >= total4) return;
    float4 v = (idx < n_user4) ? ue[idx] : ie[idx - n_user4];
    ego[idx] = v;
    ushort4 b;
    b.x = f2bf(v.x); b.y = f2bf(v.y); b.z = f2bf(v.z); b.w = f2bf(v.w);
    egob[idx] = b;
}

// pass A: per-(bucket, block) histogram via LDS — no global atomics.
__global__ void bhist_kernel(const int* __restrict__ rows, int* __restrict__ counts_t, int nnz,
                             int nbuckets) {
    __shared__ int h[BMAX];
    int tid = threadIdx.x, blk = blockIdx.x;
    for (int i = tid; i < nbuckets; i += 256) h[i] = 0;
    __syncthreads();
    int chunk = (nnz + NBLKA - 1) / NBLKA;
    int lo = blk * chunk, hi = min(nnz, lo + chunk);
    for (int e = lo + tid; e < hi; e += 256) atomicAdd(&h[rows[e] >> RB_SHIFT], 1);
    __syncthreads();
    for (int i = tid; i < nbuckets; i += 256) counts_t[blk * nbuckets + i] = h[i];
}

// scan over flat order f = bucket*NBLKA + blk, reading transposed counts.
__global__ void scan1_kernel(const int* __restrict__ counts_t, int* __restrict__ offsets,
                             int* __restrict__ blocksums, int flat, int nbuckets) {
    __shared__ int tmp[1024];
    int t = threadIdx.x;
    int g = blockIdx.x * 1024 + t;
    int x = 0;
    if (g < flat) {
        int i = g >> NBLKA_SHIFT, blk = g & (NBLKA - 1);
        x = counts_t[blk * nbuckets + i];
    }
    tmp[t] = x;
    __syncthreads();
    for (int off = 1; off < 1024; off <<= 1) {
        int y = (t >= off) ? tmp[t - off] : 0;
        __syncthreads();
        tmp[t] += y;
        __syncthreads();
    }
    if (g < flat) offsets[g + 1] = tmp[t];
    if (t == 1023) blocksums[blockIdx.x] = tmp[t];
    if (g == 0) offsets[0] = 0;
}

__global__ void scan2_kernel(int* blocksums, int nb) {
    __shared__ int tmp[1024];
    int t = threadIdx.x;
    int v = (t < nb) ? blocksums[t] : 0;
    tmp[t] = v;
    __syncthreads();
    for (int off = 1; off < 1024; off <<= 1) {
        int y = (t >= off) ? tmp[t - off] : 0;
        __syncthreads();
        tmp[t] += y;
        __syncthreads();
    }
    if (t < nb) blocksums[t] = tmp[t] - v;  // exclusive base per block
}

__global__ void scan3_kernel(int* __restrict__ offsets, const int* __restrict__ blocksums,
                             int n) {
    int g = blockIdx.x * 1024 + threadIdx.x;
    if (g < n) offsets[g + 1] += blocksums[blockIdx.x];
}

// pass B: LDS bucket-sort the block's chunk, then write back with consecutive
// lanes -> consecutive global addresses (R10: cut scattered-store transactions).
__global__ void __launch_bounds__(256) bscatter_kernel(
    const int* __restrict__ rows, const int* __restrict__ cols,
    const float* __restrict__ vals, const int* __restrict__ offsets,
    int2* __restrict__ csr_cv, int nnz, int nbuckets) {
    __shared__ int hist[BMAX];
    __shared__ int lbase[BMAX];
    __shared__ int cur[BMAX];
    __shared__ int gcur[BMAX];
    __shared__ int tsum[256];
    __shared__ int2 buf[EMAX];
    __shared__ int dst[EMAX];
    int tid = threadIdx.x, blk = blockIdx.x;
    int chunk = (nnz + NBLKA - 1) / NBLKA;
    int lo = blk * chunk, hi = min(nnz, lo + chunk);
    for (int i = tid; i < BMAX; i += 256)
        gcur[i] = (i < nbuckets) ? offsets[i * NBLKA + blk] : 0;
    for (int sub = lo; sub < hi; sub += EMAX) {
        int scount = min(EMAX, hi - sub);
        for (int i = tid; i < BMAX; i += 256) hist[i] = 0;
        __syncthreads();
        for (int e = sub + tid; e < sub + scount; e += 256)
            atomicAdd(&hist[rows[e] >> RB_SHIFT], 1);
        __syncthreads();
        int loc[4];
        int s = 0;
        int bi = tid * 4;
#pragma unroll
        for (int j = 0; j < 4; ++j) { loc[j] = s; s += hist[bi + j]; }
        tsum[tid] = s;
        __syncthreads();
        for (int off = 1; off < 256; off <<= 1) {
            int v = (tid >= off) ? tsum[tid - off] : 0;
            __syncthreads();
            tsum[tid] += v;
            __syncthreads();
        }
        int excl = tid ? tsum[tid - 1] : 0;
#pragma unroll
        for (int j = 0; j < 4; ++j) {
            lbase[bi + j] = excl + loc[j];
            cur[bi + j] = excl + loc[j];
        }
        __syncthreads();
        for (int e = sub + tid; e < sub + scount; e += 256) {
            int r = rows[e];
            int b = r >> RB_SHIFT;
            int p = atomicAdd(&cur[b], 1);
            int2 cv;
            cv.x = ((r & (RB - 1)) << 18) | cols[e];  // row_low(8b) | col(18b)
            cv.y = __float_as_int(vals[e]);
            buf[p] = cv;
            dst[p] = gcur[b] + (p - lbase[b]);
        }
        __syncthreads();
        for (int k = tid; k < scount; k += 256) csr_cv[dst[k]] = buf[k];
        __syncthreads();
        for (int i = tid; i < BMAX; i += 256) gcur[i] += hist[i];
        __syncthreads();
    }
}

// ONE-TIME sort: per bucket, counting-sort edges by row; LDS fast path, direct
// global scatter fallback for oversized buckets (replaces the ovf list — the
// fused layer kernel has no global side to fix up).
__global__ void __launch_bounds__(256) sort_kernel(
    const int* __restrict__ offsets, const int2* __restrict__ csr_cv,
    int2* __restrict__ sorted_cv, int* __restrict__ rowoff_g, int nnz, int nbuckets) {
    __shared__ int2 sorted[CAP];
    __shared__ int hist[RB];
    __shared__ int rowoff[RB + 1];
    __shared__ int cur[RB];
    int tid = threadIdx.x;
    int b = blockIdx.x;
    int s = offsets[b * NBLKA];
    int e = offsets[(b + 1) * NBLKA];
    int m = e - s;

    hist[tid] = 0;
    __syncthreads();
    for (int k = s + tid; k < e; k += 256)
        atomicAdd(&hist[((unsigned)csr_cv[k].x) >> 18], 1);
    __syncthreads();
    for (int off = 1; off < RB; off <<= 1) {
        int v = (tid >= off) ? hist[tid - off] : 0;
        __syncthreads();
        hist[tid] += v;
        __syncthreads();
    }
    rowoff[tid + 1] = hist[tid];
    if (tid == 0) rowoff[0] = 0;
    __syncthreads();
    cur[tid] = rowoff[tid];
    __syncthreads();
    if (m <= CAP) {
        for (int k = s + tid; k < e; k += 256) {
            int2 cv = csr_cv[k];
            int p = atomicAdd(&cur[((unsigned)cv.x) >> 18], 1);
            sorted[p] = cv;
        }
        __syncthreads();
        for (int k = tid; k < m; k += 256) sorted_cv[s + k] = sorted[k];
    } else {
        // rare fallback: scatter straight to global (uncoalesced, correct)
        for (int k = s + tid; k < e; k += 256) {
            int2 cv = csr_cv[k];
            int p = atomicAdd(&cur[((unsigned)cv.x) >> 18], 1);
            sorted_cv[s + p] = cv;
        }
    }
    rowoff_g[b * RB + tid] = s + rowoff[tid];
    if (b == 0 && tid == 0) rowoff_g[nbuckets * RB] = nnz;
}

// FUSED layer: spmm (side into LDS) + MFMA transform, per 64-row block.
// Reads ego_old/egob_old (stable this layer), writes ego_new/egob_new
// (ping-pong, so no intra-layer RAW across blocks). Kills the 75 MB/layer
// side HBM round-trip + 2 dispatch gaps (R10 analysis).
__global__ void __launch_bounds__(256) fused_layer_kernel(
    const uint4* __restrict__ egob_old, const float* __restrict__ ego_old,
    float* __restrict__ ego_new, ushort* __restrict__ egob_new,
    const int* __restrict__ rowoff, const int2* __restrict__ sorted_cv,
    const float* __restrict__ Wgc, const float* __restrict__ bgc,
    const float* __restrict__ Wbi, const float* __restrict__ bbi, int n) {
    __shared__ __align__(16) float sideL[64 * SPAD];
    __shared__ __align__(16) ushort sWg[DD * WT_STRIDE];
    __shared__ __align__(16) ushort sWb[DD * WT_STRIDE];
    int tid = threadIdx.x;
    for (int idx = tid; idx < DD * DD; idx += 256) {
        int k = idx >> 6, c = idx & 63;
        sWg[c * WT_STRIDE + k] = f2bf(Wgc[idx]);
        sWb[c * WT_STRIDE + k] = f2bf(Wbi[idx]);
    }
    int base64 = blockIdx.x * 64;
    int wave = tid >> 6, lane = tid & 63;
    int sub = lane >> 3, l8 = lane & 7;

    // phase 1: spmm into LDS side tile (2 passes x 4 waves x 8 rows)
#pragma unroll
    for (int pass = 0; pass < 2; ++pass) {
        int lr = pass * 32 + wave * 8 + sub;
        int row = base64 + lr;
        float acc[8] = {0.f, 0.f, 0.f, 0.f, 0.f, 0.f, 0.f, 0.f};
        if (row < n) {
            int s = rowoff[row], e = rowoff[row + 1];
            int k = s;
            for (; k + 4 <= e; k += 4) {
                int2 c0 = sorted_cv[k];
                int2 c1 = sorted_cv[k + 1];
                int2 c2 = sorted_cv[k + 2];
                int2 c3 = sorted_cv[k + 3];
                uint4 g0 = egob_old[(c0.x & COLM) * 8 + l8];
                uint4 g1 = egob_old[(c1.x & COLM) * 8 + l8];
                uint4 g2 = egob_old[(c2.x & COLM) * 8 + l8];
                uint4 g3 = egob_old[(c3.x & COLM) * 8 + l8];
                float v0 = __int_as_float(c0.y), v1 = __int_as_float(c1.y);
                float v2 = __int_as_float(c2.y), v3 = __int_as_float(c3.y);
                acc[0] += v0 * BF_LO(g0.x); acc[1] += v0 * BF_HI(g0.x);
                acc[2] += v0 * BF_LO(g0.y); acc[3] += v0 * BF_HI(g0.y);
                acc[4] += v0 * BF_LO(g0.z); acc[5] += v0 * BF_HI(g0.z);
                acc[6] += v0 * BF_LO(g0.w); acc[7] += v0 * BF_HI(g0.w);
                acc[0] += v1 * BF_LO(g1.x); acc[1] += v1 * BF_HI(g1.x);
                acc[2] += v1 * BF_LO(g1.y); acc[3] += v1 * BF_HI(g1.y);
                acc[4] += v1 * BF_LO(g1.z); acc[5] += v1 * BF_HI(g1.z);
                acc[6] += v1 * BF_LO(g1.w); acc[7] += v1 * BF_HI(g1.w);
                acc[0] += v2 * BF_LO(g2.x); acc[1] += v2 * BF_HI(g2.x);
                acc[2] += v2 * BF_LO(g2.y); acc[3] += v2 * BF_HI(g2.y);
                acc[4] += v2 * BF_LO(g2.z); acc[5] += v2 * BF_HI(g2.z);
                acc[6] += v2 * BF_LO(g2.w); acc[7] += v2 * BF_HI(g2.w);
                acc[0] += v3 * BF_LO(g3.x); acc[1] += v3 * BF_HI(g3.x);
                acc[2] += v3 * BF_LO(g3.y); acc[3] += v3 * BF_HI(g3.y);
                acc[4] += v3 * BF_LO(g3.z); acc[5] += v3 * BF_HI(g3.z);
                acc[6] += v3 * BF_LO(g3.w); acc[7] += v3 * BF_HI(g3.w);
            }
            for (; k < e; ++k) {
                int2 cv = sorted_cv[k];
                uint4 g = egob_old[(cv.x & COLM) * 8 + l8];
                float v = __int_as_float(cv.y);
                acc[0] += v * BF_LO(g.x); acc[1] += v * BF_HI(g.x);
                acc[2] += v * BF_LO(g.y); acc[3] += v * BF_HI(g.y);
                acc[4] += v * BF_LO(g.z); acc[5] += v * BF_HI(g.z);
                acc[6] += v * BF_LO(g.w); acc[7] += v * BF_HI(g.w);
            }
        }
        float4 o0 = {acc[0], acc[1], acc[2], acc[3]};
        float4 o1 = {acc[4], acc[5], acc[6], acc[7]};
        *(float4*)&sideL[lr * SPAD + l8 * 8] = o0;
        *(float4*)&sideL[lr * SPAD + l8 * 8 + 4] = o1;
    }
    __syncthreads();

    // phase 2: MFMA transform; wave handles 16-row tile
    int m = lane & 15, quad = lane >> 4;
    int lr = wave * 16 + m;
    int base = base64 + wave * 16;
    int rowc = min(base64 + lr, n - 1);

    float4 s0 = *(const float4*)&sideL[lr * SPAD + quad * 8];
    float4 s1 = *(const float4*)&sideL[lr * SPAD + quad * 8 + 4];
    float4 s2 = *(const float4*)&sideL[lr * SPAD + 32 + quad * 8];
    float4 s3 = *(const float4*)&sideL[lr * SPAD + 32 + quad * 8 + 4];
    const float4* erow = (const float4*)(ego_old + (size_t)rowc * DD);
    float4 e0 = erow[quad * 2], e1 = erow[quad * 2 + 1];
    float4 e2 = erow[8 + quad * 2], e3 = erow[8 + quad * 2 + 1];

    bf16x8 aS_lo = pack8(s0.x, s0.y, s0.z, s0.w, s1.x, s1.y, s1.z, s1.w);
    bf16x8 aS_hi = pack8(s2.x, s2.y, s2.z, s2.w, s3.x, s3.y, s3.z, s3.w);
    bf16x8 aP_lo = pack8(e0.x * s0.x, e0.y * s0.y, e0.z * s0.z, e0.w * s0.w,
                         e1.x * s1.x, e1.y * s1.y, e1.z * s1.z, e1.w * s1.w);
    bf16x8 aP_hi = pack8(e2.x * s2.x, e2.y * s2.y, e2.z * s2.z, e2.w * s2.w,
                         e3.x * s3.x, e3.y * s3.y, e3.z * s3.z, e3.w * s3.w);

    f32x4 accG[4], accB[4];
#pragma unroll
    for (int ct = 0; ct < 4; ++ct) {
        accG[ct] = (f32x4){0.f, 0.f, 0.f, 0.f};
        accB[ct] = (f32x4){0.f, 0.f, 0.f, 0.f};
    }
#pragma unroll
    for (int ct = 0; ct < 4; ++ct) {
        int col = ct * 16 + m;
        bf16x8 bg_lo = *(const bf16x8*)&sWg[col * WT_STRIDE + quad * 8];
        bf16x8 bg_hi = *(const bf16x8*)&sWg[col * WT_STRIDE + 32 + quad * 8];
        bf16x8 bb_lo = *(const bf16x8*)&sWb[col * WT_STRIDE + quad * 8];
        bf16x8 bb_hi = *(const bf16x8*)&sWb[col * WT_STRIDE + 32 + quad * 8];
        accG[ct] = __builtin_amdgcn_mfma_f32_16x16x32_bf16(aS_lo, bg_lo, accG[ct], 0, 0, 0);
        accG[ct] = __builtin_amdgcn_mfma_f32_16x16x32_bf16(aS_hi, bg_hi, accG[ct], 0, 0, 0);
        accB[ct] = __builtin_amdgcn_mfma_f32_16x16x32_bf16(aP_lo, bb_lo, accB[ct], 0, 0, 0);
        accB[ct] = __builtin_amdgcn_mfma_f32_16x16x32_bf16(aP_hi, bb_hi, accB[ct], 0, 0, 0);
    }

#pragma unroll
    for (int ct = 0; ct < 4; ++ct) {
        int col = ct * 16 + m;
        float bg = bgc[col], bb = bbi[col];
#pragma unroll
        for (int r = 0; r < 4; ++r) {
            int node = base + quad * 4 + r;
            if (node < n) {
                float o = leaky(accG[ct][r] + bg) + leaky(accB[ct][r] + bb);
                ego_new[(size_t)node * DD + col] = o;
                egob_new[(size_t)node * DD + col] = f2bf(o);
            }
        }
    }
}

__global__ void gather_kernel(const float* __restrict__ ego, const int* __restrict__ u,
                              const int* __restrict__ ii, const int* __restrict__ jj,
                              float* __restrict__ out, int layer, int B, int n_users,
                              int normalize) {
    int wid = (blockIdx.x * blockDim.x + threadIdx.x) >> 6;
    int lane = threadIdx.x & 63;
    if (wid >= 3 * B) return;
    int arr = wid / B;
    int b = wid - arr * B;
    int node = (arr == 0) ? u[b] : ((arr == 1) ? n_users + ii[b] : n_users + jj[b]);
    float v = ego[node * DD + lane];
    if (normalize) {
        float ss = v * v;
#pragma unroll
        for (int m = 32; m; m >>= 1) ss += __shfl_xor(ss, m, 64);
        v /= fmaxf(sqrtf(ss), 1e-12f);
    }
    out[wid * 256 + layer * DD + lane] = v;
}

extern "C" void kernel_launch(void* const* d_in, const int* in_sizes, int n_in,
                              void* d_out, int out_size, void* d_ws, size_t ws_size,
                              hipStream_t stream) {
    const float* user_emb = (const float*)d_in[0];
    const float* item_emb = (const float*)d_in[1];
    const float* W_gc = (const float*)d_in[2];
    const float* b_gc = (const float*)d_in[3];
    const float* W_bi = (const float*)d_in[4];
    const float* b_bi = (const float*)d_in[5];
    const float* adj_vals = (const float*)d_in[6];
    const int* adj_rows = (const int*)d_in[7];
    const int* adj_cols = (const int*)d_in[8];
    const int* u = (const int*)d_in[9];
    const int* ii = (const int*)d_in[10];
    const int* jj = (const int*)d_in[11];
    float* out = (float*)d_out;

    const int D = DD;
    int n_users = in_sizes[0] / D;
    int n_items = in_sizes[1] / D;
    int n = n_users + n_items;
    int nnz = in_sizes[6];
    int B = in_sizes[9];
    int L = in_sizes[2] / (D * D);

    int nbuckets = (n + RB - 1) / RB;      // 586
    int flat = nbuckets * NBLKA;

    char* ws = (char*)d_ws;
    auto alloc = [&](size_t bytes) {
        char* p = ws;
        ws += (bytes + 255) & ~(size_t)255;
        return p;
    };
    float* ego_a = (float*)alloc((size_t)n * D * 4);
    float* ego_b = (float*)alloc((size_t)n * D * 4);
    ushort* egob_a = (ushort*)alloc((size_t)n * D * 2);
    ushort* egob_b = (ushort*)alloc((size_t)n * D * 2);
    int* counts_t = (int*)alloc((size_t)flat * 4);
    int* offsets = (int*)alloc((size_t)(flat + 1) * 4);
    int* blocksums = (int*)alloc(4096);
    int2* csr_cv = (int2*)alloc((size_t)nnz * 8);
    int2* sorted_cv = (int2*)alloc((size_t)nnz * 8);
    int* rowoff = (int*)alloc((size_t)(nbuckets * RB + 1) * 4);

    // 1. ego = concat(user_emb, item_emb), fp32 + bf16 mirror
    int total4 = n * D / 4, nu4 = n_users * D / 4;
    concat_kernel<<<(total4 + 255) / 256, 256, 0, stream>>>(
        (const float4*)user_emb, (const float4*)item_emb, (float4*)ego_a, (ushort4*)egob_a,
        nu4, total4);

    // 2. layer-0 slice of the output (raw ego, no normalization)
    int grows = 3 * B;
    gather_kernel<<<(grows + 3) / 4, 256, 0, stream>>>(ego_a, u, ii, jj, out, 0, B, n_users, 0);

    // 3. bucketed CSR build + ONE row-sort (graph identical across layers)
    bhist_kernel<<<NBLKA, 256, 0, stream>>>(adj_rows, counts_t, nnz, nbuckets);
    int nblk1 = (flat + 1023) / 1024;
    scan1_kernel<<<nblk1, 1024, 0, stream>>>(counts_t, offsets, blocksums, flat, nbuckets);
    scan2_kernel<<<1, 1024, 0, stream>>>(blocksums, nblk1);
    scan3_kernel<<<nblk1, 1024, 0, stream>>>(offsets, blocksums, flat);
    bscatter_kernel<<<NBLKA, 256, 0, stream>>>(adj_rows, adj_cols, adj_vals, offsets, csr_cv,
                                               nnz, nbuckets);
    sort_kernel<<<nbuckets, 256, 0, stream>>>(offsets, csr_cv, sorted_cv, rowoff, nnz, nbuckets);

    // 4. layers (ping-pong ego buffers)
    float* eo = ego_a; ushort* ebo = egob_a;
    float* en = ego_b; ushort* ebn = egob_b;
    int fblocks = (n + 63) / 64;
    for (int l = 0; l < L; ++l) {
        fused_layer_kernel<<<fblocks, 256, 0, stream>>>(
            (const uint4*)ebo, eo, en, ebn, rowoff, sorted_cv,
            W_gc + (size_t)l * D * D, b_gc + (size_t)l * D,
            W_bi + (size_t)l * D * D, b_bi + (size_t)l * D, n);
        gather_kernel<<<(grows + 3) / 4, 256, 0, stream>>>(en, u, ii, jj, out, l + 1, B,
                                                           n_users, 1);
        float* tf = eo; eo = en; en = tf;
        ushort* tb = ebo; ebo = ebn; ebn = tb;
    }
}